// Round 18
// baseline (208.289 us; speedup 1.0000x reference)
//
#include <hip/hip_runtime.h>
#include <hip/hip_cooperative_groups.h>
#include <math.h>

// ---------------------------------------------------------------------------
// LorentzSelfAttention — MI355X
//
// Degenerate-clamp simplification (verified analytically, passed R1-R16):
//   u_agg_i = C*(W_i + S_i*Q_i),  W_i = sum_j p_ij V_j,  p = exp(-d^2)*dist
//   S_i = -mink(Q_i, W_i)  [R9-verified identity]
//   Y_i = mink_normalize(Q_i + u_agg_i/sum_e), |time|
//   Ztan_i = dist0*C * (2*Y0, Ys)
//
// R18 = R17 fixed: (a) coop grid 512 -> 256 blocks (1 block/CU guaranteed
// co-resident; R17's 512 @ high VGPR exceeded max -> launch error, never
// ran, out stayed zero); (b) VGPR-diet epilogue (chunked pack2, no 128-
// ushort arrays); (c) hipLaunchCooperativeKernel return code CHECKED with
// fallback to the proven R16 3-kernel path (59us floor for this round).
// Phases 2/3 process 2 tiles per block.
// ---------------------------------------------------------------------------

namespace cg = cooperative_groups;

namespace {

constexpr int Tq = 512;
constexpr int QS = 36;            // padded f32 Q row stride

#define EPSF  1e-6f
#define CINV  3.16227766e7f       // 1/sqrt(1e-15)

using short8 = __attribute__((ext_vector_type(8))) short;
using f32x4  = __attribute__((ext_vector_type(4))) float;

__device__ __forceinline__ float facosh(float x) {
    return __logf(x + __builtin_amdgcn_sqrtf(fmaf(x, x, -1.0f)));
}

__device__ __forceinline__ void cvt_hilo(float x, unsigned short& h, unsigned short& l) {
    const unsigned u = __float_as_uint(x);
    h = (unsigned short)(u >> 16);
    const float xh = __uint_as_float(u & 0xFFFF0000u);
    l = (unsigned short)(__float_as_uint(x - xh) >> 16);
}

__device__ __forceinline__ void pack2(float a, float b, unsigned& h, unsigned& l) {
    unsigned short ah, al2, bh, bl;
    cvt_hilo(a, ah, al2); cvt_hilo(b, bh, bl);
    h = (unsigned)ah | ((unsigned)bh << 16);
    l = (unsigned)al2 | ((unsigned)bl << 16);
}

__device__ __forceinline__ uint4 pack8(const unsigned short* s) {
    uint4 r;
    r.x = (unsigned)s[0] | ((unsigned)s[1] << 16);
    r.y = (unsigned)s[2] | ((unsigned)s[3] << 16);
    r.z = (unsigned)s[4] | ((unsigned)s[5] << 16);
    r.w = (unsigned)s[6] | ((unsigned)s[7] << 16);
    return r;
}

// ===========================================================================
//                    FUSED COOPERATIVE KERNEL (256 blocks)
// ===========================================================================
__global__ __launch_bounds__(256) void fused_kernel(
    const float* __restrict__ x,
    const float* __restrict__ Wq, const float* __restrict__ bq,
    const float* __restrict__ Wk, const float* __restrict__ bk,
    const float* __restrict__ Wv, const float* __restrict__ bv,
    const float* __restrict__ Wo, const float* __restrict__ bo,
    float* __restrict__ out, float* __restrict__ Qf,
    unsigned short* __restrict__ Qh, unsigned short* __restrict__ Ql,
    unsigned short* __restrict__ Kh, unsigned short* __restrict__ Kl,
    unsigned short* __restrict__ Vh, unsigned short* __restrict__ Vl,
    unsigned short* __restrict__ V2h, unsigned short* __restrict__ V2l,
    float* __restrict__ Zt)
{
    __shared__ __align__(16) unsigned char smem[37888];
    cg::grid_group grid = cg::this_grid();

    const int b = blockIdx.x;         // 0..255
    const int t = threadIdx.x;        // 0..255
    const int l = t & 63, w = t >> 6;

    // ======================= Phase 1: QKV GEMM + FL =======================
    if (b < 192) {
        unsigned short* Ah = (unsigned short*)smem;          // [64][72]
        unsigned short* Al = Ah + 64 * 72;
        unsigned short* Bh = Al + 64 * 72;
        unsigned short* Bl = Bh + 64 * 72;
        float* sT = (float*)smem;                            // [64][65] aliases Ah/Al

        const int bx = b % 12, by = b / 12;
        const int n0 = bx * 64, m0 = by * 64;
        const int wr = (w >> 1) * 32, wc = (w & 1) * 32;
        const int fr = l & 15, fk = (l >> 4) * 8;

        const int sr  = t >> 2;
        const int seg = (t & 3) * 16;
        const int ob  = n0 + sr;
        const float* WselB = (ob < 256) ? Wq : (ob < 512 ? Wk : Wv);
        const int obr = ob & 255;

        f32x4 acc[2][2];
        #pragma unroll
        for (int mt = 0; mt < 2; ++mt)
            #pragma unroll
            for (int nt = 0; nt < 2; ++nt) acc[mt][nt] = (f32x4){0.f, 0.f, 0.f, 0.f};

        for (int k0 = 0; k0 < 512; k0 += 64) {
            {
                const float* xp = x + (m0 + sr) * 512 + k0 + seg;
                unsigned short hh[16], ll[16];
                #pragma unroll
                for (int c = 0; c < 4; ++c) {
                    const float4 v = *reinterpret_cast<const float4*>(xp + c * 4);
                    cvt_hilo(v.x, hh[c*4+0], ll[c*4+0]);
                    cvt_hilo(v.y, hh[c*4+1], ll[c*4+1]);
                    cvt_hilo(v.z, hh[c*4+2], ll[c*4+2]);
                    cvt_hilo(v.w, hh[c*4+3], ll[c*4+3]);
                }
                *reinterpret_cast<uint4*>(&Ah[sr * 72 + seg])     = pack8(hh);
                *reinterpret_cast<uint4*>(&Ah[sr * 72 + seg + 8]) = pack8(hh + 8);
                *reinterpret_cast<uint4*>(&Al[sr * 72 + seg])     = pack8(ll);
                *reinterpret_cast<uint4*>(&Al[sr * 72 + seg + 8]) = pack8(ll + 8);

                const float* wp = WselB + obr * 512 + k0 + seg;
                #pragma unroll
                for (int c = 0; c < 4; ++c) {
                    const float4 v = *reinterpret_cast<const float4*>(wp + c * 4);
                    cvt_hilo(v.x, hh[c*4+0], ll[c*4+0]);
                    cvt_hilo(v.y, hh[c*4+1], ll[c*4+1]);
                    cvt_hilo(v.z, hh[c*4+2], ll[c*4+2]);
                    cvt_hilo(v.w, hh[c*4+3], ll[c*4+3]);
                }
                *reinterpret_cast<uint4*>(&Bh[sr * 72 + seg])     = pack8(hh);
                *reinterpret_cast<uint4*>(&Bh[sr * 72 + seg + 8]) = pack8(hh + 8);
                *reinterpret_cast<uint4*>(&Bl[sr * 72 + seg])     = pack8(ll);
                *reinterpret_cast<uint4*>(&Bl[sr * 72 + seg + 8]) = pack8(ll + 8);
            }
            __syncthreads();

            #pragma unroll
            for (int ks = 0; ks < 2; ++ks) {
                const int kb = ks * 32 + fk;
                short8 ah[2], al_[2], bh[2], bl_[2];
                #pragma unroll
                for (int mt = 0; mt < 2; ++mt) {
                    ah[mt]  = *reinterpret_cast<const short8*>(&Ah[(wr + mt * 16 + fr) * 72 + kb]);
                    al_[mt] = *reinterpret_cast<const short8*>(&Al[(wr + mt * 16 + fr) * 72 + kb]);
                }
                #pragma unroll
                for (int nt = 0; nt < 2; ++nt) {
                    bh[nt]  = *reinterpret_cast<const short8*>(&Bh[(wc + nt * 16 + fr) * 72 + kb]);
                    bl_[nt] = *reinterpret_cast<const short8*>(&Bl[(wc + nt * 16 + fr) * 72 + kb]);
                }
                #pragma unroll
                for (int mt = 0; mt < 2; ++mt)
                    #pragma unroll
                    for (int nt = 0; nt < 2; ++nt) {
                        acc[mt][nt] = __builtin_amdgcn_mfma_f32_16x16x32_bf16(
                            ah[mt], bh[nt], acc[mt][nt], 0, 0, 0);
                        acc[mt][nt] = __builtin_amdgcn_mfma_f32_16x16x32_bf16(
                            ah[mt], bl_[nt], acc[mt][nt], 0, 0, 0);
                        acc[mt][nt] = __builtin_amdgcn_mfma_f32_16x16x32_bf16(
                            al_[mt], bh[nt], acc[mt][nt], 0, 0, 0);
                    }
            }
            __syncthreads();
        }

        #pragma unroll
        for (int mt = 0; mt < 2; ++mt)
            #pragma unroll
            for (int nt = 0; nt < 2; ++nt)
                #pragma unroll
                for (int r = 0; r < 4; ++r)
                    sT[(wr + mt * 16 + (l >> 4) * 4 + r) * 65 + wc + nt * 16 + (l & 15)] =
                        acc[mt][nt][r];
        __syncthreads();

        if (t < 128) {
            const int m = t >> 1, half = t & 1;
            const int row = m0 + m;
            const int bb = row >> 9, tt = row & 511;
            const int which = n0 >> 8;
            const int h = ((n0 & 255) >> 5) + half;
            const int bh2 = bb * 8 + h;
            const float* bsel = (which == 0) ? bq : (which == 1 ? bk : bv);

            float ys[32];
            float s2 = 0.f;
            #pragma unroll
            for (int k = 0; k < 32; ++k) {
                ys[k] = sT[m * 65 + half * 32 + k] + bsel[h * 32 + k];
                s2 = fmaf(ys[k], ys[k], s2);
            }
            const float rr = __builtin_amdgcn_sqrtf(s2);
            const float rs = fminf(fmaxf(rr, 1e-12f), 18.0f);
            const float e  = __expf(rs);
            const float ei = __builtin_amdgcn_rcpf(e);
            const float ch = 0.5f * (e + ei);
            float sc = 0.5f * (e - ei) / rs;
            if (rs < 1e-3f) sc = fmaf(rs * rs, 1.0f / 6.0f, 1.0f);
            float y0 = ch;
            float mink = -y0 * y0;
            #pragma unroll
            for (int k = 0; k < 32; ++k) { ys[k] *= sc; mink = fmaf(ys[k], ys[k], mink); }
            const float inv = __builtin_amdgcn_rsqf(fmaxf(fabsf(mink), 1e-15f));
            y0 = fabsf(y0 * inv);

            const long rbase = (long)(bh2 * Tq + tt) * 64;
            const float sgn = (which == 0) ? 1.f : -1.f;
            unsigned short* Xh = (which == 0) ? Qh : (which == 1 ? Kh : Vh);
            unsigned short* Xl = (which == 0) ? Ql : (which == 1 ? Kl : Vl);

            #pragma unroll
            for (int c = 0; c < 4; ++c) {
                float f0 = ys[c*8+0] * inv, f1 = ys[c*8+1] * inv;
                float f2 = ys[c*8+2] * inv, f3 = ys[c*8+3] * inv;
                float f4 = ys[c*8+4] * inv, f5 = ys[c*8+5] * inv;
                float f6 = ys[c*8+6] * inv, f7 = ys[c*8+7] * inv;
                if (which == 0) {
                    float* qp = Qf + (bh2 * Tq + tt) * QS + c * 8;
                    float4 a; a.x = f0; a.y = f1; a.z = f2; a.w = f3;
                    float4 d; d.x = f4; d.y = f5; d.z = f6; d.w = f7;
                    *reinterpret_cast<float4*>(qp) = a;
                    *reinterpret_cast<float4*>(qp + 4) = d;
                } else if (which == 2) {
                    const long v2b = (long)bh2 * 48 * Tq + tt;
                    unsigned short hh2, lo2;
                    cvt_hilo(f0, hh2, lo2); V2h[v2b + (c*8+1)*Tq] = hh2; V2l[v2b + (c*8+1)*Tq] = lo2;
                    cvt_hilo(f1, hh2, lo2); V2h[v2b + (c*8+2)*Tq] = hh2; V2l[v2b + (c*8+2)*Tq] = lo2;
                    cvt_hilo(f2, hh2, lo2); V2h[v2b + (c*8+3)*Tq] = hh2; V2l[v2b + (c*8+3)*Tq] = lo2;
                    cvt_hilo(f3, hh2, lo2); V2h[v2b + (c*8+4)*Tq] = hh2; V2l[v2b + (c*8+4)*Tq] = lo2;
                    cvt_hilo(f4, hh2, lo2); V2h[v2b + (c*8+5)*Tq] = hh2; V2l[v2b + (c*8+5)*Tq] = lo2;
                    cvt_hilo(f5, hh2, lo2); V2h[v2b + (c*8+6)*Tq] = hh2; V2l[v2b + (c*8+6)*Tq] = lo2;
                    cvt_hilo(f6, hh2, lo2); V2h[v2b + (c*8+7)*Tq] = hh2; V2l[v2b + (c*8+7)*Tq] = lo2;
                    cvt_hilo(f7, hh2, lo2); V2h[v2b + (c*8+8)*Tq] = hh2; V2l[v2b + (c*8+8)*Tq] = lo2;
                }
                uint4 H, L;
                pack2(sgn * f0, sgn * f1, H.x, L.x);
                pack2(sgn * f2, sgn * f3, H.y, L.y);
                pack2(sgn * f4, sgn * f5, H.z, L.z);
                pack2(sgn * f6, sgn * f7, H.w, L.w);
                *reinterpret_cast<uint4*>(&Xh[rbase + c * 8]) = H;
                *reinterpret_cast<uint4*>(&Xl[rbase + c * 8]) = L;
            }
            // tail: k=32 is +y0 for all three; rest zero
            {
                uint4 H, L;
                pack2(y0, 0.f, H.x, L.x);
                H.y = H.z = H.w = 0u; L.y = L.z = L.w = 0u;
                *reinterpret_cast<uint4*>(&Xh[rbase + 32]) = H;
                *reinterpret_cast<uint4*>(&Xl[rbase + 32]) = L;
                uint4 Z; Z.x = Z.y = Z.z = Z.w = 0u;
                *reinterpret_cast<uint4*>(&Xh[rbase + 40]) = Z;
                *reinterpret_cast<uint4*>(&Xl[rbase + 40]) = Z;
                *reinterpret_cast<uint4*>(&Xh[rbase + 48]) = Z;
                *reinterpret_cast<uint4*>(&Xl[rbase + 48]) = Z;
                *reinterpret_cast<uint4*>(&Xh[rbase + 56]) = Z;
                *reinterpret_cast<uint4*>(&Xl[rbase + 56]) = Z;
                if (which == 0) {
                    float* qp = Qf + (bh2 * Tq + tt) * QS;
                    float4 tail; tail.x = y0; tail.y = 0.f; tail.z = 0.f; tail.w = 0.f;
                    *reinterpret_cast<float4*>(qp + 32) = tail;
                } else if (which == 2) {
                    const long v2b = (long)bh2 * 48 * Tq + tt;
                    unsigned short hh2, lo2;
                    cvt_hilo(y0, hh2, lo2);
                    V2h[v2b] = hh2; V2l[v2b] = lo2;
                }
            }
        }
    }
    __threadfence();
    grid.sync();

    // ======================= Phase 2: attention (2 tiles) =================
    {
        unsigned short* sPh = (unsigned short*)smem;         // [16][528]
        unsigned short* sPl = sPh + 16 * 528;
        float* sSe = (float*)(smem + 33792);                 // [4][16]
        float* sW  = (float*)(smem + 34048);                 // [16][48]
        const int fr = l & 15, fk = (l >> 4) * 8;

        #pragma unroll 1
        for (int tile = 0; tile < 2; ++tile) {
            const int tb = b * 2 + tile;      // 0..511
            const int bh = tb >> 5;
            const int i0 = (tb & 31) * 16;

            short8 qh[2], ql[2];
            {
                const long qb = (long)(bh * Tq + i0 + fr) * 64;
                #pragma unroll
                for (int ks = 0; ks < 2; ++ks) {
                    qh[ks] = *reinterpret_cast<const short8*>(&Qh[qb + ks * 32 + fk]);
                    ql[ks] = *reinterpret_cast<const short8*>(&Ql[qb + ks * 32 + fk]);
                }
            }

            float seLoc[4] = {0.f, 0.f, 0.f, 0.f};
            #pragma unroll 2
            for (int c = 0; c < 8; ++c) {
                const int j0 = (w * 8 + c) * 16;
                const long kb = (long)(bh * Tq + j0 + fr) * 64;
                f32x4 aK = (f32x4){0.f, 0.f, 0.f, 0.f};
                f32x4 aV = (f32x4){0.f, 0.f, 0.f, 0.f};
                #pragma unroll
                for (int ks = 0; ks < 2; ++ks) {
                    const long o = kb + ks * 32 + fk;
                    const short8 bkh = *reinterpret_cast<const short8*>(&Kh[o]);
                    const short8 bkl = *reinterpret_cast<const short8*>(&Kl[o]);
                    const short8 bvh = *reinterpret_cast<const short8*>(&Vh[o]);
                    const short8 bvl = *reinterpret_cast<const short8*>(&Vl[o]);
                    aK = __builtin_amdgcn_mfma_f32_16x16x32_bf16(qh[ks], bkh, aK, 0, 0, 0);
                    aK = __builtin_amdgcn_mfma_f32_16x16x32_bf16(qh[ks], bkl, aK, 0, 0, 0);
                    aK = __builtin_amdgcn_mfma_f32_16x16x32_bf16(ql[ks], bkh, aK, 0, 0, 0);
                    aV = __builtin_amdgcn_mfma_f32_16x16x32_bf16(qh[ks], bvh, aV, 0, 0, 0);
                    aV = __builtin_amdgcn_mfma_f32_16x16x32_bf16(qh[ks], bvl, aV, 0, 0, 0);
                    aV = __builtin_amdgcn_mfma_f32_16x16x32_bf16(ql[ks], bvh, aV, 0, 0, 0);
                }
                #pragma unroll
                for (int r = 0; r < 4; ++r) {
                    const int i = (l >> 4) * 4 + r;
                    const int j = j0 + (l & 15);
                    const float d  = facosh(fmaxf(aK[r], 1.0f + EPSF));
                    const float al = fmaxf(aV[r], 1.0f + EPSF);
                    const float e  = __expf(-d * d);
                    const float p  = e * facosh(al);
                    seLoc[r] += e;
                    unsigned short hh, lo;
                    cvt_hilo(p, hh, lo);
                    sPh[i * 528 + j] = hh; sPl[i * 528 + j] = lo;
                }
            }
            #pragma unroll
            for (int r = 0; r < 4; ++r) {
                float v = seLoc[r];
                v += __shfl_xor(v, 1, 64);
                v += __shfl_xor(v, 2, 64);
                v += __shfl_xor(v, 4, 64);
                v += __shfl_xor(v, 8, 64);
                if ((l & 15) == 0) sSe[w * 16 + (l >> 4) * 4 + r] = v;
            }
            __syncthreads();

            if (w < 3) {
                const int a0 = w * 16;
                const long vb = (long)bh * 48 * Tq + (long)(a0 + fr) * Tq;
                f32x4 aW = (f32x4){0.f, 0.f, 0.f, 0.f};
                #pragma unroll 2
                for (int ks = 0; ks < 16; ++ks) {
                    const int ko = ks * 32 + fk;
                    const short8 ph = *reinterpret_cast<const short8*>(&sPh[fr * 528 + ko]);
                    const short8 pl = *reinterpret_cast<const short8*>(&sPl[fr * 528 + ko]);
                    const short8 v2h = *reinterpret_cast<const short8*>(&V2h[vb + ko]);
                    const short8 v2l = *reinterpret_cast<const short8*>(&V2l[vb + ko]);
                    aW = __builtin_amdgcn_mfma_f32_16x16x32_bf16(ph, v2h, aW, 0, 0, 0);
                    aW = __builtin_amdgcn_mfma_f32_16x16x32_bf16(ph, v2l, aW, 0, 0, 0);
                    aW = __builtin_amdgcn_mfma_f32_16x16x32_bf16(pl, v2h, aW, 0, 0, 0);
                }
                #pragma unroll
                for (int r = 0; r < 4; ++r)
                    sW[((l >> 4) * 4 + r) * 48 + a0 + (l & 15)] = aW[r];
            }
            __syncthreads();

            if (t < 16) {
                const int i = t;
                const float seT = sSe[0 * 16 + i] + sSe[1 * 16 + i] +
                                  sSe[2 * 16 + i] + sSe[3 * 16 + i];
                const float* qrow = Qf + (long)(bh * Tq + i0 + i) * QS;
                const float q0 = qrow[32];
                float dot = 0.f;
                #pragma unroll
                for (int a = 1; a < 33; ++a) dot = fmaf(qrow[a - 1], sW[i * 48 + a], dot);
                const float S = q0 * sW[i * 48] - dot;
                const float cs = CINV * __builtin_amdgcn_rcpf(seT);
                const float y0 = fmaf(cs, fmaf(S, q0, sW[i * 48]), q0);
                float mink = -y0 * y0;
                float yv[32];
                #pragma unroll
                for (int a = 1; a < 33; ++a) {
                    const float qa = qrow[a - 1];
                    const float ya = fmaf(cs, fmaf(S, qa, sW[i * 48 + a]), qa);
                    yv[a - 1] = ya;
                    mink = fmaf(ya, ya, mink);
                }
                const float inv = __builtin_amdgcn_rsqf(fmaxf(fabsf(mink), 1e-15f));
                const float Y0 = fabsf(y0 * inv);
                const float dist0 = facosh(fmaxf(Y0, 1.0f + EPSF));
                const float coef = dist0 * CINV;
                const int bb = bh >> 3, h = bh & 7;
                float* zp = Zt + ((bb * Tq + (i0 + i)) * 264) + h * 33;
                zp[0] = coef * (2.0f * Y0);
                #pragma unroll
                for (int a = 1; a < 33; ++a) zp[a] = coef * (yv[a - 1] * inv);
            }
            __syncthreads();   // protect LDS reuse by next tile
        }
    }
    __threadfence();
    grid.sync();

    // ======================= Phase 3: output GEMM (2 tiles) ===============
    {
        float* AsT = (float*)smem;           // [24][36]
        float* BsT = AsT + 24 * 36;
        const int tx = t & 15, ty = t >> 4;
        const int ar = t >> 3, ac = t & 7;

        #pragma unroll 1
        for (int tile = 0; tile < 2; ++tile) {
            const int tb = b * 2 + tile;      // 0..511
            const int n0 = (tb & 15) * 32;
            const int m0 = (tb >> 4) * 32;

            float acc2[2][2];
            acc2[0][0] = acc2[0][1] = acc2[1][0] = acc2[1][1] = 0.f;

            for (int k0 = 0; k0 < 264; k0 += 24) {
                #pragma unroll
                for (int s = 0; s < 3; ++s) {
                    AsT[(ac + s * 8) * 36 + ar] = Zt[(m0 + ar) * 264 + k0 + ac + s * 8];
                    BsT[(ac + s * 8) * 36 + ar] = Wo[(n0 + ar) * 264 + k0 + ac + s * 8];
                }
                __syncthreads();
                #pragma unroll
                for (int kk = 0; kk < 24; ++kk) {
                    const float2 a2 = *reinterpret_cast<const float2*>(&AsT[kk * 36 + ty * 2]);
                    const float2 b2 = *reinterpret_cast<const float2*>(&BsT[kk * 36 + tx * 2]);
                    acc2[0][0] = fmaf(a2.x, b2.x, acc2[0][0]);
                    acc2[0][1] = fmaf(a2.x, b2.y, acc2[0][1]);
                    acc2[1][0] = fmaf(a2.y, b2.x, acc2[1][0]);
                    acc2[1][1] = fmaf(a2.y, b2.y, acc2[1][1]);
                }
                __syncthreads();
            }
            #pragma unroll
            for (int c = 0; c < 2; ++c) {
                const int o = n0 + tx * 2 + c;
                const float bias = bo[o];
                #pragma unroll
                for (int r = 0; r < 2; ++r)
                    out[(m0 + ty * 2 + r) * 512 + o] = acc2[r][c] + bias;
            }
        }
    }
}

// ===========================================================================
//                    FALLBACK: R16 three-kernel path (proven 59us)
// ===========================================================================
__global__ __launch_bounds__(256) void gemm_qkv_mfma_kernel(
    const float* __restrict__ x,
    const float* __restrict__ Wq, const float* __restrict__ bq,
    const float* __restrict__ Wk, const float* __restrict__ bk,
    const float* __restrict__ Wv, const float* __restrict__ bv,
    float* __restrict__ Qf,
    unsigned short* __restrict__ Qh, unsigned short* __restrict__ Ql,
    unsigned short* __restrict__ Kh, unsigned short* __restrict__ Kl,
    unsigned short* __restrict__ Vh, unsigned short* __restrict__ Vl,
    unsigned short* __restrict__ V2h, unsigned short* __restrict__ V2l)
{
    __shared__ unsigned short Ah[64][72], Al[64][72];
    __shared__ unsigned short Bh[64][72], Bl[64][72];
    __shared__ float sT[64][65];

    const int n0 = blockIdx.x * 64;
    const int m0 = blockIdx.y * 64;
    const int t  = threadIdx.x;
    const int l  = t & 63, w = t >> 6;
    const int wr = (w >> 1) * 32, wc = (w & 1) * 32;
    const int fr = l & 15, fk = (l >> 4) * 8;

    const int sr  = t >> 2;
    const int seg = (t & 3) * 16;
    const int ob  = n0 + sr;
    const float* WselB = (ob < 256) ? Wq : (ob < 512 ? Wk : Wv);
    const int obr = ob & 255;

    f32x4 acc[2][2];
    #pragma unroll
    for (int mt = 0; mt < 2; ++mt)
        #pragma unroll
        for (int nt = 0; nt < 2; ++nt) acc[mt][nt] = (f32x4){0.f, 0.f, 0.f, 0.f};

    for (int k0 = 0; k0 < 512; k0 += 64) {
        {
            const float* xp = x + (m0 + sr) * 512 + k0 + seg;
            unsigned short hh[16], ll[16];
            #pragma unroll
            for (int c = 0; c < 4; ++c) {
                const float4 v = *reinterpret_cast<const float4*>(xp + c * 4);
                cvt_hilo(v.x, hh[c*4+0], ll[c*4+0]);
                cvt_hilo(v.y, hh[c*4+1], ll[c*4+1]);
                cvt_hilo(v.z, hh[c*4+2], ll[c*4+2]);
                cvt_hilo(v.w, hh[c*4+3], ll[c*4+3]);
            }
            *reinterpret_cast<uint4*>(&Ah[sr][seg])     = pack8(hh);
            *reinterpret_cast<uint4*>(&Ah[sr][seg + 8]) = pack8(hh + 8);
            *reinterpret_cast<uint4*>(&Al[sr][seg])     = pack8(ll);
            *reinterpret_cast<uint4*>(&Al[sr][seg + 8]) = pack8(ll + 8);

            const float* wp = WselB + obr * 512 + k0 + seg;
            #pragma unroll
            for (int c = 0; c < 4; ++c) {
                const float4 v = *reinterpret_cast<const float4*>(wp + c * 4);
                cvt_hilo(v.x, hh[c*4+0], ll[c*4+0]);
                cvt_hilo(v.y, hh[c*4+1], ll[c*4+1]);
                cvt_hilo(v.z, hh[c*4+2], ll[c*4+2]);
                cvt_hilo(v.w, hh[c*4+3], ll[c*4+3]);
            }
            *reinterpret_cast<uint4*>(&Bh[sr][seg])     = pack8(hh);
            *reinterpret_cast<uint4*>(&Bh[sr][seg + 8]) = pack8(hh + 8);
            *reinterpret_cast<uint4*>(&Bl[sr][seg])     = pack8(ll);
            *reinterpret_cast<uint4*>(&Bl[sr][seg + 8]) = pack8(ll + 8);
        }
        __syncthreads();

        #pragma unroll
        for (int ks = 0; ks < 2; ++ks) {
            const int kb = ks * 32 + fk;
            short8 ah[2], al_[2], bh[2], bl_[2];
            #pragma unroll
            for (int mt = 0; mt < 2; ++mt) {
                ah[mt]  = *reinterpret_cast<const short8*>(&Ah[wr + mt * 16 + fr][kb]);
                al_[mt] = *reinterpret_cast<const short8*>(&Al[wr + mt * 16 + fr][kb]);
            }
            #pragma unroll
            for (int nt = 0; nt < 2; ++nt) {
                bh[nt]  = *reinterpret_cast<const short8*>(&Bh[wc + nt * 16 + fr][kb]);
                bl_[nt] = *reinterpret_cast<const short8*>(&Bl[wc + nt * 16 + fr][kb]);
            }
            #pragma unroll
            for (int mt = 0; mt < 2; ++mt)
                #pragma unroll
                for (int nt = 0; nt < 2; ++nt) {
                    acc[mt][nt] = __builtin_amdgcn_mfma_f32_16x16x32_bf16(
                        ah[mt], bh[nt], acc[mt][nt], 0, 0, 0);
                    acc[mt][nt] = __builtin_amdgcn_mfma_f32_16x16x32_bf16(
                        ah[mt], bl_[nt], acc[mt][nt], 0, 0, 0);
                    acc[mt][nt] = __builtin_amdgcn_mfma_f32_16x16x32_bf16(
                        al_[mt], bh[nt], acc[mt][nt], 0, 0, 0);
                }
        }
        __syncthreads();
    }

    #pragma unroll
    for (int mt = 0; mt < 2; ++mt)
        #pragma unroll
        for (int nt = 0; nt < 2; ++nt)
            #pragma unroll
            for (int r = 0; r < 4; ++r)
                sT[wr + mt * 16 + (l >> 4) * 4 + r][wc + nt * 16 + (l & 15)] =
                    acc[mt][nt][r];
    __syncthreads();

    if (t < 128) {
        const int m = t >> 1, half = t & 1;
        const int row = m0 + m;
        const int b = row >> 9, tt = row & 511;
        const int which = n0 >> 8;
        const int h = ((n0 & 255) >> 5) + half;
        const int bh2 = b * 8 + h;
        const float* bsel = (which == 0) ? bq : (which == 1 ? bk : bv);

        float ys[32];
        float s2 = 0.f;
        #pragma unroll
        for (int k = 0; k < 32; ++k) {
            ys[k] = sT[m][half * 32 + k] + bsel[h * 32 + k];
            s2 = fmaf(ys[k], ys[k], s2);
        }
        const float rr = __builtin_amdgcn_sqrtf(s2);
        const float rs = fminf(fmaxf(rr, 1e-12f), 18.0f);
        const float e  = __expf(rs);
        const float ei = __builtin_amdgcn_rcpf(e);
        const float ch = 0.5f * (e + ei);
        float sc = 0.5f * (e - ei) / rs;
        if (rs < 1e-3f) sc = fmaf(rs * rs, 1.0f / 6.0f, 1.0f);
        float y0 = ch;
        float mink = -y0 * y0;
        #pragma unroll
        for (int k = 0; k < 32; ++k) { ys[k] *= sc; mink = fmaf(ys[k], ys[k], mink); }
        const float inv = __builtin_amdgcn_rsqf(fmaxf(fabsf(mink), 1e-15f));
        y0 = fabsf(y0 * inv);

        const long rbase = (long)(bh2 * Tq + tt) * 64;
        const float sgn = (which == 0) ? 1.f : -1.f;
        unsigned short* Xh = (which == 0) ? Qh : (which == 1 ? Kh : Vh);
        unsigned short* Xl = (which == 0) ? Ql : (which == 1 ? Kl : Vl);

        #pragma unroll
        for (int c = 0; c < 4; ++c) {
            float f0 = ys[c*8+0] * inv, f1 = ys[c*8+1] * inv;
            float f2 = ys[c*8+2] * inv, f3 = ys[c*8+3] * inv;
            float f4 = ys[c*8+4] * inv, f5 = ys[c*8+5] * inv;
            float f6 = ys[c*8+6] * inv, f7 = ys[c*8+7] * inv;
            if (which == 0) {
                float* qp = Qf + (bh2 * Tq + tt) * QS + c * 8;
                float4 a; a.x = f0; a.y = f1; a.z = f2; a.w = f3;
                float4 d; d.x = f4; d.y = f5; d.z = f6; d.w = f7;
                *reinterpret_cast<float4*>(qp) = a;
                *reinterpret_cast<float4*>(qp + 4) = d;
            } else if (which == 2) {
                const long v2b = (long)bh2 * 48 * Tq + tt;
                unsigned short hh2, lo2;
                cvt_hilo(f0, hh2, lo2); V2h[v2b + (c*8+1)*Tq] = hh2; V2l[v2b + (c*8+1)*Tq] = lo2;
                cvt_hilo(f1, hh2, lo2); V2h[v2b + (c*8+2)*Tq] = hh2; V2l[v2b + (c*8+2)*Tq] = lo2;
                cvt_hilo(f2, hh2, lo2); V2h[v2b + (c*8+3)*Tq] = hh2; V2l[v2b + (c*8+3)*Tq] = lo2;
                cvt_hilo(f3, hh2, lo2); V2h[v2b + (c*8+4)*Tq] = hh2; V2l[v2b + (c*8+4)*Tq] = lo2;
                cvt_hilo(f4, hh2, lo2); V2h[v2b + (c*8+5)*Tq] = hh2; V2l[v2b + (c*8+5)*Tq] = lo2;
                cvt_hilo(f5, hh2, lo2); V2h[v2b + (c*8+6)*Tq] = hh2; V2l[v2b + (c*8+6)*Tq] = lo2;
                cvt_hilo(f6, hh2, lo2); V2h[v2b + (c*8+7)*Tq] = hh2; V2l[v2b + (c*8+7)*Tq] = lo2;
                cvt_hilo(f7, hh2, lo2); V2h[v2b + (c*8+8)*Tq] = hh2; V2l[v2b + (c*8+8)*Tq] = lo2;
            }
            uint4 H, L;
            pack2(sgn * f0, sgn * f1, H.x, L.x);
            pack2(sgn * f2, sgn * f3, H.y, L.y);
            pack2(sgn * f4, sgn * f5, H.z, L.z);
            pack2(sgn * f6, sgn * f7, H.w, L.w);
            *reinterpret_cast<uint4*>(&Xh[rbase + c * 8]) = H;
            *reinterpret_cast<uint4*>(&Xl[rbase + c * 8]) = L;
        }
        {
            uint4 H, L;
            pack2(y0, 0.f, H.x, L.x);
            H.y = H.z = H.w = 0u; L.y = L.z = L.w = 0u;
            *reinterpret_cast<uint4*>(&Xh[rbase + 32]) = H;
            *reinterpret_cast<uint4*>(&Xl[rbase + 32]) = L;
            uint4 Z; Z.x = Z.y = Z.z = Z.w = 0u;
            *reinterpret_cast<uint4*>(&Xh[rbase + 40]) = Z;
            *reinterpret_cast<uint4*>(&Xl[rbase + 40]) = Z;
            *reinterpret_cast<uint4*>(&Xh[rbase + 48]) = Z;
            *reinterpret_cast<uint4*>(&Xl[rbase + 48]) = Z;
            *reinterpret_cast<uint4*>(&Xh[rbase + 56]) = Z;
            *reinterpret_cast<uint4*>(&Xl[rbase + 56]) = Z;
            if (which == 0) {
                float* qp = Qf + (bh2 * Tq + tt) * QS;
                float4 tail; tail.x = y0; tail.y = 0.f; tail.z = 0.f; tail.w = 0.f;
                *reinterpret_cast<float4*>(qp + 32) = tail;
            } else if (which == 2) {
                const long v2b = (long)bh2 * 48 * Tq + tt;
                unsigned short hh2, lo2;
                cvt_hilo(y0, hh2, lo2);
                V2h[v2b] = hh2; V2l[v2b] = lo2;
            }
        }
    }
}

__global__ __launch_bounds__(256) void attn_mfma_kernel(
    const float* __restrict__ Qf,
    const unsigned short* __restrict__ Qh, const unsigned short* __restrict__ Ql,
    const unsigned short* __restrict__ Kh, const unsigned short* __restrict__ Kl,
    const unsigned short* __restrict__ Vh, const unsigned short* __restrict__ Vl,
    const unsigned short* __restrict__ V2h, const unsigned short* __restrict__ V2l,
    float* __restrict__ Ztan)
{
    __shared__ unsigned short sPh[16][528], sPl[16][528];
    __shared__ float sSe[4][16];
    __shared__ float sW[16][48];

    const int bh = blockIdx.y;
    const int i0 = blockIdx.x * 16;
    const int t  = threadIdx.x;
    const int l  = t & 63, w = t >> 6;
    const int fr = l & 15, fk = (l >> 4) * 8;

    short8 qh[2], ql[2];
    {
        const long qb = (long)(bh * Tq + i0 + fr) * 64;
        #pragma unroll
        for (int ks = 0; ks < 2; ++ks) {
            qh[ks] = *reinterpret_cast<const short8*>(&Qh[qb + ks * 32 + fk]);
            ql[ks] = *reinterpret_cast<const short8*>(&Ql[qb + ks * 32 + fk]);
        }
    }

    float seLoc[4] = {0.f, 0.f, 0.f, 0.f};
    #pragma unroll 2
    for (int c = 0; c < 8; ++c) {
        const int j0 = (w * 8 + c) * 16;
        const long kb = (long)(bh * Tq + j0 + fr) * 64;
        f32x4 aK = (f32x4){0.f, 0.f, 0.f, 0.f};
        f32x4 aV = (f32x4){0.f, 0.f, 0.f, 0.f};
        #pragma unroll
        for (int ks = 0; ks < 2; ++ks) {
            const long o = kb + ks * 32 + fk;
            const short8 bkh = *reinterpret_cast<const short8*>(&Kh[o]);
            const short8 bkl = *reinterpret_cast<const short8*>(&Kl[o]);
            const short8 bvh = *reinterpret_cast<const short8*>(&Vh[o]);
            const short8 bvl = *reinterpret_cast<const short8*>(&Vl[o]);
            aK = __builtin_amdgcn_mfma_f32_16x16x32_bf16(qh[ks], bkh, aK, 0, 0, 0);
            aK = __builtin_amdgcn_mfma_f32_16x16x32_bf16(qh[ks], bkl, aK, 0, 0, 0);
            aK = __builtin_amdgcn_mfma_f32_16x16x32_bf16(ql[ks], bkh, aK, 0, 0, 0);
            aV = __builtin_amdgcn_mfma_f32_16x16x32_bf16(qh[ks], bvh, aV, 0, 0, 0);
            aV = __builtin_amdgcn_mfma_f32_16x16x32_bf16(qh[ks], bvl, aV, 0, 0, 0);
            aV = __builtin_amdgcn_mfma_f32_16x16x32_bf16(ql[ks], bvh, aV, 0, 0, 0);
        }
        #pragma unroll
        for (int r = 0; r < 4; ++r) {
            const int i = (l >> 4) * 4 + r;
            const int j = j0 + (l & 15);
            const float d  = facosh(fmaxf(aK[r], 1.0f + EPSF));
            const float al = fmaxf(aV[r], 1.0f + EPSF);
            const float e  = __expf(-d * d);
            const float p  = e * facosh(al);
            seLoc[r] += e;
            unsigned short hh, lo;
            cvt_hilo(p, hh, lo);
            sPh[i][j] = hh; sPl[i][j] = lo;
        }
    }
    #pragma unroll
    for (int r = 0; r < 4; ++r) {
        float v = seLoc[r];
        v += __shfl_xor(v, 1, 64);
        v += __shfl_xor(v, 2, 64);
        v += __shfl_xor(v, 4, 64);
        v += __shfl_xor(v, 8, 64);
        if ((l & 15) == 0) sSe[w][(l >> 4) * 4 + r] = v;
    }
    __syncthreads();

    if (w < 3) {
        const int a0 = w * 16;
        const long vb = (long)bh * 48 * Tq + (long)(a0 + fr) * Tq;
        f32x4 aW = (f32x4){0.f, 0.f, 0.f, 0.f};
        #pragma unroll 2
        for (int ks = 0; ks < 16; ++ks) {
            const int ko = ks * 32 + fk;
            const short8 ph = *reinterpret_cast<const short8*>(&sPh[fr][ko]);
            const short8 pl = *reinterpret_cast<const short8*>(&sPl[fr][ko]);
            const short8 v2h = *reinterpret_cast<const short8*>(&V2h[vb + ko]);
            const short8 v2l = *reinterpret_cast<const short8*>(&V2l[vb + ko]);
            aW = __builtin_amdgcn_mfma_f32_16x16x32_bf16(ph, v2h, aW, 0, 0, 0);
            aW = __builtin_amdgcn_mfma_f32_16x16x32_bf16(ph, v2l, aW, 0, 0, 0);
            aW = __builtin_amdgcn_mfma_f32_16x16x32_bf16(pl, v2h, aW, 0, 0, 0);
        }
        #pragma unroll
        for (int r = 0; r < 4; ++r)
            sW[(l >> 4) * 4 + r][a0 + (l & 15)] = aW[r];
    }
    __syncthreads();

    if (t < 16) {
        const int i = t;
        const float seT = sSe[0][i] + sSe[1][i] + sSe[2][i] + sSe[3][i];
        const float* qrow = Qf + (long)(bh * Tq + i0 + i) * QS;
        const float q0 = qrow[32];
        float dot = 0.f;
        #pragma unroll
        for (int a = 1; a < 33; ++a) dot = fmaf(qrow[a - 1], sW[i][a], dot);
        const float S = q0 * sW[i][0] - dot;
        const float cs = CINV * __builtin_amdgcn_rcpf(seT);
        const float y0 = fmaf(cs, fmaf(S, q0, sW[i][0]), q0);
        float mink = -y0 * y0;
        float yv[32];
        #pragma unroll
        for (int a = 1; a < 33; ++a) {
            const float qa = qrow[a - 1];
            const float ya = fmaf(cs, fmaf(S, qa, sW[i][a]), qa);
            yv[a - 1] = ya;
            mink = fmaf(ya, ya, mink);
        }
        const float inv = __builtin_amdgcn_rsqf(fmaxf(fabsf(mink), 1e-15f));
        const float Y0 = fabsf(y0 * inv);
        const float dist0 = facosh(fmaxf(Y0, 1.0f + EPSF));
        const float coef = dist0 * CINV;
        const int b = bh >> 3, h = bh & 7;
        float* zp = Ztan + ((b * Tq + (i0 + i)) * 264) + h * 33;
        zp[0] = coef * (2.0f * Y0);
        #pragma unroll
        for (int a = 1; a < 33; ++a) zp[a] = coef * (yv[a - 1] * inv);
    }
}

__global__ __launch_bounds__(256) void out_gemm_kernel(
    const float* __restrict__ Ztan, const float* __restrict__ Wo,
    const float* __restrict__ bo, float* __restrict__ out)
{
    __shared__ float AsT[24][36];
    __shared__ float BsT[24][36];
    const int n0 = blockIdx.x * 32;
    const int m0 = blockIdx.y * 32;
    const int t  = threadIdx.x;
    const int tx = t & 15, ty = t >> 4;
    const int ar = t >> 3, ac = t & 7;

    float acc[2][2];
    acc[0][0] = acc[0][1] = acc[1][0] = acc[1][1] = 0.f;

    for (int k0 = 0; k0 < 264; k0 += 24) {
        #pragma unroll
        for (int s = 0; s < 3; ++s) {
            AsT[ac + s * 8][ar] = Ztan[(m0 + ar) * 264 + k0 + ac + s * 8];
            BsT[ac + s * 8][ar] = Wo[(n0 + ar) * 264 + k0 + ac + s * 8];
        }
        __syncthreads();
        #pragma unroll
        for (int kk = 0; kk < 24; ++kk) {
            const float2 a2 = *reinterpret_cast<const float2*>(&AsT[kk][ty * 2]);
            const float2 b2 = *reinterpret_cast<const float2*>(&BsT[kk][tx * 2]);
            acc[0][0] = fmaf(a2.x, b2.x, acc[0][0]);
            acc[0][1] = fmaf(a2.x, b2.y, acc[0][1]);
            acc[1][0] = fmaf(a2.y, b2.x, acc[1][0]);
            acc[1][1] = fmaf(a2.y, b2.y, acc[1][1]);
        }
        __syncthreads();
    }
    #pragma unroll
    for (int c = 0; c < 2; ++c) {
        const int o = n0 + tx * 2 + c;
        const float bias = bo[o];
        #pragma unroll
        for (int r = 0; r < 2; ++r)
            out[(m0 + ty * 2 + r) * 512 + o] = acc[r][c] + bias;
    }
}

} // namespace

// ---------------------------------------------------------------------------
extern "C" void kernel_launch(void* const* d_in, const int* in_sizes, int n_in,
                              void* d_out, int out_size, void* d_ws, size_t ws_size,
                              hipStream_t stream)
{
    const float* x  = (const float*)d_in[0];
    const float* Wq = (const float*)d_in[1];
    const float* bq = (const float*)d_in[2];
    const float* Wk = (const float*)d_in[3];
    const float* bk = (const float*)d_in[4];
    const float* Wv = (const float*)d_in[5];
    const float* bv = (const float*)d_in[6];
    const float* Wo = (const float*)d_in[7];
    const float* bo = (const float*)d_in[8];
    float* out = (float*)d_out;

    float* ws = (float*)d_ws;
    float* Qf = ws;                                   // 294912
    unsigned short* Qh  = (unsigned short*)(ws + 294912);
    unsigned short* Ql  = (unsigned short*)(ws + 557056);
    unsigned short* Kh  = (unsigned short*)(ws + 819200);
    unsigned short* Kl  = (unsigned short*)(ws + 1081344);
    unsigned short* Vh  = (unsigned short*)(ws + 1343488);
    unsigned short* Vl  = (unsigned short*)(ws + 1605632);
    unsigned short* V2h = (unsigned short*)(ws + 1867776);
    unsigned short* V2l = (unsigned short*)(ws + 2064384);
    float* Zt = ws + 2260992;                         // 270336

    void* args[] = {
        (void*)&x, (void*)&Wq, (void*)&bq, (void*)&Wk, (void*)&bk,
        (void*)&Wv, (void*)&bv, (void*)&Wo, (void*)&bo,
        (void*)&out, (void*)&Qf,
        (void*)&Qh, (void*)&Ql, (void*)&Kh, (void*)&Kl,
        (void*)&Vh, (void*)&Vl, (void*)&V2h, (void*)&V2l,
        (void*)&Zt
    };
    hipError_t err = hipLaunchCooperativeKernel((const void*)fused_kernel,
                                                dim3(256), dim3(256),
                                                args, 0, stream);
    if (err != hipSuccess) {
        // fallback: proven R16 3-kernel path
        gemm_qkv_mfma_kernel<<<dim3(12, 16), 256, 0, stream>>>(
            x, Wq, bq, Wk, bk, Wv, bv, Qf, Qh, Ql, Kh, Kl, Vh, Vl, V2h, V2l);
        attn_mfma_kernel<<<dim3(32, 16), 256, 0, stream>>>(
            Qf, Qh, Ql, Kh, Kl, Vh, Vl, V2h, V2l, Zt);
        out_gemm_kernel<<<dim3(16, 32), 256, 0, stream>>>(Zt, Wo, bo, out);
    }
}

// Round 19
// 58.454 us; speedup vs baseline: 3.5633x; 3.5633x over previous
//
#include <hip/hip_runtime.h>
#include <math.h>

// ---------------------------------------------------------------------------
// LorentzSelfAttention — MI355X
//
// Degenerate-clamp simplification (verified analytically, passed R1-R18):
//   u_agg_i = C*(W_i + S_i*Q_i),  W_i = sum_j p_ij V_j,  p = exp(-d^2)*dist
//   S_i = -mink(Q_i, W_i)  [R9-verified identity]
//   Y_i = mink_normalize(Q_i + u_agg_i/sum_e), |time|
//   Ztan_i = dist0*C * (2*Y0, Ys)
//
// R19 = R16 exactly + attn unrolls 2->4 (GEMM1, GEMM2). R18's coop-fusion
// experiment gave the first clean profile: VALUBusy 5%, MfmaUtil 1.3% =>
// total real work ~10-12us; the 59us R16 path is in-kernel latency exposure
// at 2 waves/SIMD. R15->R16 proved unroll depth directly converts to time
// (-9.3us for 1->2); this doubles in-flight loads again. Coop fusion itself
// REGRESSED 3.3x (grid.sync + 1-block/CU + cold caches) — abandoned.
// ---------------------------------------------------------------------------

namespace {

constexpr int Tq = 512;
constexpr int QS = 36;            // padded f32 Q row stride

#define EPSF  1e-6f
#define CINV  3.16227766e7f       // 1/sqrt(1e-15)

using short8 = __attribute__((ext_vector_type(8))) short;
using f32x4  = __attribute__((ext_vector_type(4))) float;

__device__ __forceinline__ float facosh(float x) {
    return __logf(x + __builtin_amdgcn_sqrtf(fmaf(x, x, -1.0f)));
}

__device__ __forceinline__ void cvt_hilo(float x, unsigned short& h, unsigned short& l) {
    const unsigned u = __float_as_uint(x);
    h = (unsigned short)(u >> 16);
    const float xh = __uint_as_float(u & 0xFFFF0000u);
    l = (unsigned short)(__float_as_uint(x - xh) >> 16);
}

__device__ __forceinline__ uint4 pack8(const unsigned short* s) {
    uint4 r;
    r.x = (unsigned)s[0] | ((unsigned)s[1] << 16);
    r.y = (unsigned)s[2] | ((unsigned)s[3] << 16);
    r.z = (unsigned)s[4] | ((unsigned)s[5] << 16);
    r.w = (unsigned)s[6] | ((unsigned)s[7] << 16);
    return r;
}

// ---------------- Kernel 1: QKV GEMM via MFMA + bias + FL + bf16 emit ------
// grid (12, 16): n0 = bx*64 (2 heads of one of q/k/v), m0 = by*64 rows.
__global__ __launch_bounds__(256) void gemm_qkv_mfma_kernel(
    const float* __restrict__ x,
    const float* __restrict__ Wq, const float* __restrict__ bq,
    const float* __restrict__ Wk, const float* __restrict__ bk,
    const float* __restrict__ Wv, const float* __restrict__ bv,
    float* __restrict__ Qf,
    unsigned short* __restrict__ Qh, unsigned short* __restrict__ Ql,
    unsigned short* __restrict__ Kh, unsigned short* __restrict__ Kl,
    unsigned short* __restrict__ Vh, unsigned short* __restrict__ Vl,
    unsigned short* __restrict__ V2h, unsigned short* __restrict__ V2l)
{
    __shared__ unsigned short Ah[64][72], Al[64][72];
    __shared__ unsigned short Bh[64][72], Bl[64][72];
    __shared__ float sT[64][65];

    const int n0 = blockIdx.x * 64;
    const int m0 = blockIdx.y * 64;
    const int t  = threadIdx.x;
    const int l  = t & 63, w = t >> 6;
    const int wr = (w >> 1) * 32, wc = (w & 1) * 32;
    const int fr = l & 15, fk = (l >> 4) * 8;

    const int sr  = t >> 2;
    const int seg = (t & 3) * 16;
    const int ob  = n0 + sr;
    const float* WselB = (ob < 256) ? Wq : (ob < 512 ? Wk : Wv);
    const int obr = ob & 255;

    f32x4 acc[2][2];
    #pragma unroll
    for (int mt = 0; mt < 2; ++mt)
        #pragma unroll
        for (int nt = 0; nt < 2; ++nt) acc[mt][nt] = (f32x4){0.f, 0.f, 0.f, 0.f};

    for (int k0 = 0; k0 < 512; k0 += 64) {
        {
            const float* xp = x + (m0 + sr) * 512 + k0 + seg;
            unsigned short hh[16], ll[16];
            #pragma unroll
            for (int c = 0; c < 4; ++c) {
                const float4 v = *reinterpret_cast<const float4*>(xp + c * 4);
                cvt_hilo(v.x, hh[c*4+0], ll[c*4+0]);
                cvt_hilo(v.y, hh[c*4+1], ll[c*4+1]);
                cvt_hilo(v.z, hh[c*4+2], ll[c*4+2]);
                cvt_hilo(v.w, hh[c*4+3], ll[c*4+3]);
            }
            *reinterpret_cast<uint4*>(&Ah[sr][seg])     = pack8(hh);
            *reinterpret_cast<uint4*>(&Ah[sr][seg + 8]) = pack8(hh + 8);
            *reinterpret_cast<uint4*>(&Al[sr][seg])     = pack8(ll);
            *reinterpret_cast<uint4*>(&Al[sr][seg + 8]) = pack8(ll + 8);

            const float* wp = WselB + obr * 512 + k0 + seg;
            #pragma unroll
            for (int c = 0; c < 4; ++c) {
                const float4 v = *reinterpret_cast<const float4*>(wp + c * 4);
                cvt_hilo(v.x, hh[c*4+0], ll[c*4+0]);
                cvt_hilo(v.y, hh[c*4+1], ll[c*4+1]);
                cvt_hilo(v.z, hh[c*4+2], ll[c*4+2]);
                cvt_hilo(v.w, hh[c*4+3], ll[c*4+3]);
            }
            *reinterpret_cast<uint4*>(&Bh[sr][seg])     = pack8(hh);
            *reinterpret_cast<uint4*>(&Bh[sr][seg + 8]) = pack8(hh + 8);
            *reinterpret_cast<uint4*>(&Bl[sr][seg])     = pack8(ll);
            *reinterpret_cast<uint4*>(&Bl[sr][seg + 8]) = pack8(ll + 8);
        }
        __syncthreads();

        #pragma unroll
        for (int ks = 0; ks < 2; ++ks) {
            const int kb = ks * 32 + fk;
            short8 ah[2], al_[2], bh[2], bl_[2];
            #pragma unroll
            for (int mt = 0; mt < 2; ++mt) {
                ah[mt]  = *reinterpret_cast<const short8*>(&Ah[wr + mt * 16 + fr][kb]);
                al_[mt] = *reinterpret_cast<const short8*>(&Al[wr + mt * 16 + fr][kb]);
            }
            #pragma unroll
            for (int nt = 0; nt < 2; ++nt) {
                bh[nt]  = *reinterpret_cast<const short8*>(&Bh[wc + nt * 16 + fr][kb]);
                bl_[nt] = *reinterpret_cast<const short8*>(&Bl[wc + nt * 16 + fr][kb]);
            }
            #pragma unroll
            for (int mt = 0; mt < 2; ++mt)
                #pragma unroll
                for (int nt = 0; nt < 2; ++nt) {
                    acc[mt][nt] = __builtin_amdgcn_mfma_f32_16x16x32_bf16(
                        ah[mt], bh[nt], acc[mt][nt], 0, 0, 0);
                    acc[mt][nt] = __builtin_amdgcn_mfma_f32_16x16x32_bf16(
                        ah[mt], bl_[nt], acc[mt][nt], 0, 0, 0);
                    acc[mt][nt] = __builtin_amdgcn_mfma_f32_16x16x32_bf16(
                        al_[mt], bh[nt], acc[mt][nt], 0, 0, 0);
                }
        }
        __syncthreads();
    }

    #pragma unroll
    for (int mt = 0; mt < 2; ++mt)
        #pragma unroll
        for (int nt = 0; nt < 2; ++nt)
            #pragma unroll
            for (int r = 0; r < 4; ++r)
                sT[wr + mt * 16 + (l >> 4) * 4 + r][wc + nt * 16 + (l & 15)] =
                    acc[mt][nt][r];
    __syncthreads();

    // ---- FL lift + packed bf16 emission -----------------------------------
    if (t < 128) {
        const int m = t >> 1, half = t & 1;
        const int row = m0 + m;
        const int b = row >> 9, tt = row & 511;
        const int which = n0 >> 8;
        const int h = ((n0 & 255) >> 5) + half;
        const int bh2 = b * 8 + h;
        const float* bsel = (which == 0) ? bq : (which == 1 ? bk : bv);

        float zv[32];
        float s2 = 0.f;
        #pragma unroll
        for (int k = 0; k < 32; ++k) {
            zv[k] = sT[m][half * 32 + k] + bsel[h * 32 + k];
            s2 = fmaf(zv[k], zv[k], s2);
        }
        const float rr = __builtin_amdgcn_sqrtf(s2);
        const float rs = fminf(fmaxf(rr, 1e-12f), 18.0f);
        const float e  = __expf(rs);
        const float ei = __builtin_amdgcn_rcpf(e);
        const float ch = 0.5f * (e + ei);
        float sc = 0.5f * (e - ei) / rs;
        if (rs < 1e-3f) sc = fmaf(rs * rs, 1.0f / 6.0f, 1.0f);
        float y0 = ch;
        float ys[32];
        float mink = -y0 * y0;
        #pragma unroll
        for (int k = 0; k < 32; ++k) { ys[k] = sc * zv[k]; mink = fmaf(ys[k], ys[k], mink); }
        const float inv = __builtin_amdgcn_rsqf(fmaxf(fabsf(mink), 1e-15f));
        y0 = fabsf(y0 * inv);

        const long rbase = (long)(bh2 * Tq + tt) * 64;
        unsigned short hbuf[64], lbuf[64];
        #pragma unroll
        for (int k = 33; k < 64; ++k) { hbuf[k] = 0; lbuf[k] = 0; }

        if (which == 0) {
            float* qp = Qf + (bh2 * Tq + tt) * QS;
            #pragma unroll
            for (int c = 0; c < 8; ++c) {
                float4 v4;
                v4.x = ys[c*4+0] * inv; v4.y = ys[c*4+1] * inv;
                v4.z = ys[c*4+2] * inv; v4.w = ys[c*4+3] * inv;
                *reinterpret_cast<float4*>(qp + c * 4) = v4;
                cvt_hilo(v4.x, hbuf[c*4+0], lbuf[c*4+0]);
                cvt_hilo(v4.y, hbuf[c*4+1], lbuf[c*4+1]);
                cvt_hilo(v4.z, hbuf[c*4+2], lbuf[c*4+2]);
                cvt_hilo(v4.w, hbuf[c*4+3], lbuf[c*4+3]);
            }
            float4 tail; tail.x = y0; tail.y = 0.f; tail.z = 0.f; tail.w = 0.f;
            *reinterpret_cast<float4*>(qp + 32) = tail;
            cvt_hilo(y0, hbuf[32], lbuf[32]);
            #pragma unroll
            for (int c = 0; c < 8; ++c) {
                *reinterpret_cast<uint4*>(&Qh[rbase + c * 8]) = pack8(hbuf + c * 8);
                *reinterpret_cast<uint4*>(&Ql[rbase + c * 8]) = pack8(lbuf + c * 8);
            }
        } else if (which == 1) {
            #pragma unroll
            for (int k = 0; k < 32; ++k)
                cvt_hilo(-ys[k] * inv, hbuf[k], lbuf[k]);
            cvt_hilo(y0, hbuf[32], lbuf[32]);
            #pragma unroll
            for (int c = 0; c < 8; ++c) {
                *reinterpret_cast<uint4*>(&Kh[rbase + c * 8]) = pack8(hbuf + c * 8);
                *reinterpret_cast<uint4*>(&Kl[rbase + c * 8]) = pack8(lbuf + c * 8);
            }
        } else {
            const long v2b = (long)bh2 * 48 * Tq + tt;
            unsigned short hh, lo;
            #pragma unroll
            for (int k = 0; k < 32; ++k) {
                const float v = ys[k] * inv;
                cvt_hilo(-v, hbuf[k], lbuf[k]);
                cvt_hilo(v, hh, lo);
                V2h[v2b + (1 + k) * Tq] = hh; V2l[v2b + (1 + k) * Tq] = lo;
            }
            cvt_hilo(y0, hbuf[32], lbuf[32]);
            V2h[v2b] = hbuf[32]; V2l[v2b] = lbuf[32];
            #pragma unroll
            for (int c = 0; c < 8; ++c) {
                *reinterpret_cast<uint4*>(&Vh[rbase + c * 8]) = pack8(hbuf + c * 8);
                *reinterpret_cast<uint4*>(&Vl[rbase + c * 8]) = pack8(lbuf + c * 8);
            }
        }
    }
}

// ---------------- Kernel 2: attention via 3 MFMA GEMMs ---------------------
// grid (32, 16): 16 rows x full 512 cols per block. 256 threads = 4 waves.
__global__ __launch_bounds__(256) void attn_mfma_kernel(
    const float* __restrict__ Qf,
    const unsigned short* __restrict__ Qh, const unsigned short* __restrict__ Ql,
    const unsigned short* __restrict__ Kh, const unsigned short* __restrict__ Kl,
    const unsigned short* __restrict__ Vh, const unsigned short* __restrict__ Vl,
    const unsigned short* __restrict__ V2h, const unsigned short* __restrict__ V2l,
    float* __restrict__ Ztan)
{
    __shared__ unsigned short sPh[16][528], sPl[16][528];
    __shared__ float sSe[4][16];
    __shared__ float sW[16][48];

    const int bh = blockIdx.y;
    const int i0 = blockIdx.x * 16;
    const int t  = threadIdx.x;
    const int l  = t & 63, w = t >> 6;
    const int fr = l & 15, fk = (l >> 4) * 8;

    // A-fragments of Q (same for all waves; 16 rows)
    short8 qh[2], ql[2];
    {
        const long qb = (long)(bh * Tq + i0 + fr) * 64;
        #pragma unroll
        for (int ks = 0; ks < 2; ++ks) {
            qh[ks] = *reinterpret_cast<const short8*>(&Qh[qb + ks * 32 + fk]);
            ql[ks] = *reinterpret_cast<const short8*>(&Ql[qb + ks * 32 + fk]);
        }
    }

    // ---- GEMM1 (ip via K) + GEMM1b (al via V) + elementwise p -------------
    float seLoc[4] = {0.f, 0.f, 0.f, 0.f};
    #pragma unroll 4
    for (int c = 0; c < 8; ++c) {
        const int j0 = (w * 8 + c) * 16;
        const long kb = (long)(bh * Tq + j0 + fr) * 64;
        f32x4 aK = (f32x4){0.f, 0.f, 0.f, 0.f};
        f32x4 aV = (f32x4){0.f, 0.f, 0.f, 0.f};
        #pragma unroll
        for (int ks = 0; ks < 2; ++ks) {
            const long o = kb + ks * 32 + fk;
            const short8 bkh = *reinterpret_cast<const short8*>(&Kh[o]);
            const short8 bkl = *reinterpret_cast<const short8*>(&Kl[o]);
            const short8 bvh = *reinterpret_cast<const short8*>(&Vh[o]);
            const short8 bvl = *reinterpret_cast<const short8*>(&Vl[o]);
            aK = __builtin_amdgcn_mfma_f32_16x16x32_bf16(qh[ks], bkh, aK, 0, 0, 0);
            aK = __builtin_amdgcn_mfma_f32_16x16x32_bf16(qh[ks], bkl, aK, 0, 0, 0);
            aK = __builtin_amdgcn_mfma_f32_16x16x32_bf16(ql[ks], bkh, aK, 0, 0, 0);
            aV = __builtin_amdgcn_mfma_f32_16x16x32_bf16(qh[ks], bvh, aV, 0, 0, 0);
            aV = __builtin_amdgcn_mfma_f32_16x16x32_bf16(qh[ks], bvl, aV, 0, 0, 0);
            aV = __builtin_amdgcn_mfma_f32_16x16x32_bf16(ql[ks], bvh, aV, 0, 0, 0);
        }
        #pragma unroll
        for (int r = 0; r < 4; ++r) {
            const int i = (l >> 4) * 4 + r;
            const int j = j0 + (l & 15);
            const float d  = facosh(fmaxf(aK[r], 1.0f + EPSF));
            const float al = fmaxf(aV[r], 1.0f + EPSF);
            const float e  = __expf(-d * d);
            const float p  = e * facosh(al);
            seLoc[r] += e;
            unsigned short hh, lo;
            cvt_hilo(p, hh, lo);
            sPh[i][j] = hh; sPl[i][j] = lo;
        }
    }
    #pragma unroll
    for (int r = 0; r < 4; ++r) {
        float v = seLoc[r];
        v += __shfl_xor(v, 1, 64);
        v += __shfl_xor(v, 2, 64);
        v += __shfl_xor(v, 4, 64);
        v += __shfl_xor(v, 8, 64);
        if ((l & 15) == 0) sSe[w][(l >> 4) * 4 + r] = v;
    }
    __syncthreads();

    // ---- GEMM2: W[16][48] = p[16][512] . V2^T (waves 0..2, one a-tile) ----
    if (w < 3) {
        const int a0 = w * 16;
        const long vb = (long)bh * 48 * Tq + (long)(a0 + fr) * Tq;
        f32x4 aW = (f32x4){0.f, 0.f, 0.f, 0.f};
        #pragma unroll 4
        for (int ks = 0; ks < 16; ++ks) {
            const int ko = ks * 32 + fk;
            const short8 ph = *reinterpret_cast<const short8*>(&sPh[fr][ko]);
            const short8 pl = *reinterpret_cast<const short8*>(&sPl[fr][ko]);
            const short8 v2h = *reinterpret_cast<const short8*>(&V2h[vb + ko]);
            const short8 v2l = *reinterpret_cast<const short8*>(&V2l[vb + ko]);
            aW = __builtin_amdgcn_mfma_f32_16x16x32_bf16(ph, v2h, aW, 0, 0, 0);
            aW = __builtin_amdgcn_mfma_f32_16x16x32_bf16(ph, v2l, aW, 0, 0, 0);
            aW = __builtin_amdgcn_mfma_f32_16x16x32_bf16(pl, v2h, aW, 0, 0, 0);
        }
        #pragma unroll
        for (int r = 0; r < 4; ++r)
            sW[(l >> 4) * 4 + r][a0 + (l & 15)] = aW[r];
    }
    __syncthreads();

    // ---- P5: S identity, normalize, exp_map, origin log -------------------
    if (t < 16) {
        const int i = t;
        const float seT = sSe[0][i] + sSe[1][i] + sSe[2][i] + sSe[3][i];
        const float* qrow = Qf + (long)(bh * Tq + i0 + i) * QS;
        const float q0 = qrow[32];
        float dot = 0.f;
        #pragma unroll
        for (int a = 1; a < 33; ++a) dot = fmaf(qrow[a - 1], sW[i][a], dot);
        const float S = q0 * sW[i][0] - dot;
        const float cs = CINV * __builtin_amdgcn_rcpf(seT);
        const float y0 = fmaf(cs, fmaf(S, q0, sW[i][0]), q0);
        float mink = -y0 * y0;
        float yv[32];
        #pragma unroll
        for (int a = 1; a < 33; ++a) {
            const float qa = qrow[a - 1];
            const float ya = fmaf(cs, fmaf(S, qa, sW[i][a]), qa);
            yv[a - 1] = ya;
            mink = fmaf(ya, ya, mink);
        }
        const float inv = __builtin_amdgcn_rsqf(fmaxf(fabsf(mink), 1e-15f));
        const float Y0 = fabsf(y0 * inv);
        const float dist0 = facosh(fmaxf(Y0, 1.0f + EPSF));
        const float coef = dist0 * CINV;
        const int b = bh >> 3, h = bh & 7;
        float* zp = Ztan + ((b * Tq + (i0 + i)) * 264) + h * 33;
        zp[0] = coef * (2.0f * Y0);
        #pragma unroll
        for (int a = 1; a < 33; ++a) zp[a] = coef * (yv[a - 1] * inv);
    }
}

// ---------------- Kernel 3: Z = Ztan(1024x264) @ Wo^T + bo, BK=24 ----------
__global__ __launch_bounds__(256) void out_gemm_kernel(
    const float* __restrict__ Ztan, const float* __restrict__ Wo,
    const float* __restrict__ bo, float* __restrict__ out)
{
    __shared__ float AsT[24][36];
    __shared__ float BsT[24][36];
    const int n0 = blockIdx.x * 32;
    const int m0 = blockIdx.y * 32;
    const int t  = threadIdx.x;
    const int tx = t & 15, ty = t >> 4;
    const int ar = t >> 3, ac = t & 7;

    float acc[2][2];
    acc[0][0] = acc[0][1] = acc[1][0] = acc[1][1] = 0.f;

    for (int k0 = 0; k0 < 264; k0 += 24) {
        #pragma unroll
        for (int s = 0; s < 3; ++s) {
            AsT[ac + s * 8][ar] = Ztan[(m0 + ar) * 264 + k0 + ac + s * 8];
            BsT[ac + s * 8][ar] = Wo[(n0 + ar) * 264 + k0 + ac + s * 8];
        }
        __syncthreads();
        #pragma unroll
        for (int kk = 0; kk < 24; ++kk) {
            const float2 a2 = *reinterpret_cast<const float2*>(&AsT[kk][ty * 2]);
            const float2 b2 = *reinterpret_cast<const float2*>(&BsT[kk][tx * 2]);
            acc[0][0] = fmaf(a2.x, b2.x, acc[0][0]);
            acc[0][1] = fmaf(a2.x, b2.y, acc[0][1]);
            acc[1][0] = fmaf(a2.y, b2.x, acc[1][0]);
            acc[1][1] = fmaf(a2.y, b2.y, acc[1][1]);
        }
        __syncthreads();
    }
    #pragma unroll
    for (int c = 0; c < 2; ++c) {
        const int o = n0 + tx * 2 + c;
        const float bias = bo[o];
        #pragma unroll
        for (int r = 0; r < 2; ++r)
            out[(m0 + ty * 2 + r) * 512 + o] = acc[r][c] + bias;
    }
}

} // namespace

// ---------------------------------------------------------------------------
extern "C" void kernel_launch(void* const* d_in, const int* in_sizes, int n_in,
                              void* d_out, int out_size, void* d_ws, size_t ws_size,
                              hipStream_t stream)
{
    const float* x  = (const float*)d_in[0];
    const float* Wq = (const float*)d_in[1];
    const float* bq = (const float*)d_in[2];
    const float* Wk = (const float*)d_in[3];
    const float* bk = (const float*)d_in[4];
    const float* Wv = (const float*)d_in[5];
    const float* bv = (const float*)d_in[6];
    const float* Wo = (const float*)d_in[7];
    const float* bo = (const float*)d_in[8];
    float* out = (float*)d_out;

    float* ws = (float*)d_ws;
    float* Qf = ws;                                   // 294912
    unsigned short* Qh  = (unsigned short*)(ws + 294912);
    unsigned short* Ql  = (unsigned short*)(ws + 557056);
    unsigned short* Kh  = (unsigned short*)(ws + 819200);
    unsigned short* Kl  = (unsigned short*)(ws + 1081344);
    unsigned short* Vh  = (unsigned short*)(ws + 1343488);
    unsigned short* Vl  = (unsigned short*)(ws + 1605632);
    unsigned short* V2h = (unsigned short*)(ws + 1867776);
    unsigned short* V2l = (unsigned short*)(ws + 2064384);
    float* Zt = ws + 2260992;                         // 270336

    gemm_qkv_mfma_kernel<<<dim3(12, 16), 256, 0, stream>>>(
        x, Wq, bq, Wk, bk, Wv, bv, Qf, Qh, Ql, Kh, Kl, Vh, Vl, V2h, V2l);
    attn_mfma_kernel<<<dim3(32, 16), 256, 0, stream>>>(
        Qf, Qh, Ql, Kh, Kl, Vh, Vl, V2h, V2l, Zt);
    out_gemm_kernel<<<dim3(16, 32), 256, 0, stream>>>(Zt, Wo, bo, out);
}

// Round 20
// 49.262 us; speedup vs baseline: 4.2282x; 1.1866x over previous
//
#include <hip/hip_runtime.h>
#include <math.h>

// ---------------------------------------------------------------------------
// LorentzSelfAttention — MI355X
//
// Degenerate-clamp simplification (verified analytically, passed R1-R19):
//   u_agg_i = C*(W_i + S_i*Q_i),  W_i = sum_j p_ij V_j,  p = exp(-d^2)*dist
//   S_i = -mink(Q_i, W_i)  [R9-verified identity]
//   Y_i = mink_normalize(Q_i + u_agg_i/sum_e), |time|
//   Ztan_i = dist0*C * (2*Y0, Ys)
//
// R20: occupancy + work-drop round (R19 proved unroll saturated; R18 profile
// proved ~10us issue work vs ~45us latency exposure):
//  1. attn: 512-thread blocks (8 waves) -> 4 waves/SIMD (was 2). GEMM2 on
//     6 waves (3 a-tiles x 2 k-halves, partials folded in P5).
//  2. alpha/P path single bf16-RNE (score path keeps hi/lo for exp(-d^2)):
//     Vl/V2l/sPl deleted; GEMM1b & GEMM2 3->1 mfma; LDS 33.8->23.5KB.
//  3. qkv: 16-row tiles, grid (12,64)=768 blocks = 3 blocks/CU (was 0.75).
// ---------------------------------------------------------------------------

namespace {

constexpr int Tq = 512;
constexpr int QS = 36;            // padded f32 Q row stride

#define EPSF  1e-6f
#define CINV  3.16227766e7f       // 1/sqrt(1e-15)

using short8 = __attribute__((ext_vector_type(8))) short;
using f32x4  = __attribute__((ext_vector_type(4))) float;

__device__ __forceinline__ float facosh(float x) {
    return __logf(x + __builtin_amdgcn_sqrtf(fmaf(x, x, -1.0f)));
}

__device__ __forceinline__ void cvt_hilo(float x, unsigned short& h, unsigned short& l) {
    const unsigned u = __float_as_uint(x);
    h = (unsigned short)(u >> 16);
    const float xh = __uint_as_float(u & 0xFFFF0000u);
    l = (unsigned short)(__float_as_uint(x - xh) >> 16);
}

__device__ __forceinline__ unsigned short cvt_rne(float x) {
    const unsigned u = __float_as_uint(x);
    return (unsigned short)((u + 0x7FFFu + ((u >> 16) & 1u)) >> 16);
}

__device__ __forceinline__ uint4 pack8(const unsigned short* s) {
    uint4 r;
    r.x = (unsigned)s[0] | ((unsigned)s[1] << 16);
    r.y = (unsigned)s[2] | ((unsigned)s[3] << 16);
    r.z = (unsigned)s[4] | ((unsigned)s[5] << 16);
    r.w = (unsigned)s[6] | ((unsigned)s[7] << 16);
    return r;
}

// ---------------- Kernel 1: QKV GEMM, 16x64 tiles, grid (12,64) ------------
__global__ __launch_bounds__(256) void gemm_qkv_mfma_kernel(
    const float* __restrict__ x,
    const float* __restrict__ Wq, const float* __restrict__ bq,
    const float* __restrict__ Wk, const float* __restrict__ bk,
    const float* __restrict__ Wv, const float* __restrict__ bv,
    float* __restrict__ Qf,
    unsigned short* __restrict__ Qh, unsigned short* __restrict__ Ql,
    unsigned short* __restrict__ Kh, unsigned short* __restrict__ Kl,
    unsigned short* __restrict__ Vh, unsigned short* __restrict__ V2h)
{
    __shared__ unsigned short Ah[16][72], Al[16][72];
    __shared__ unsigned short Bh[64][72], Bl[64][72];
    __shared__ float sT[16][65];      // NOTE: separate (Ah/Al too small to alias)

    const int n0 = blockIdx.x * 64;
    const int m0 = blockIdx.y * 16;
    const int t  = threadIdx.x;
    const int l  = t & 63, w = t >> 6;
    const int wc = w * 16;
    const int fr = l & 15, fk = (l >> 4) * 8;

    // staging indices
    const int arow = t >> 4, akseg = (t & 15) * 4;     // A: 4 elems/thread
    const int brow = t >> 2, bkseg = (t & 3) * 16;     // B: 16 elems/thread
    const int ob  = n0 + brow;
    const float* WselB = (ob < 256) ? Wq : (ob < 512 ? Wk : Wv);
    const int obr = ob & 255;

    f32x4 acc = (f32x4){0.f, 0.f, 0.f, 0.f};

    for (int k0 = 0; k0 < 512; k0 += 64) {
        {
            const float4 av = *reinterpret_cast<const float4*>(
                &x[(m0 + arow) * 512 + k0 + akseg]);
            unsigned short h4[4], l4[4];
            cvt_hilo(av.x, h4[0], l4[0]); cvt_hilo(av.y, h4[1], l4[1]);
            cvt_hilo(av.z, h4[2], l4[2]); cvt_hilo(av.w, h4[3], l4[3]);
            uint2 H, L;
            H.x = (unsigned)h4[0] | ((unsigned)h4[1] << 16);
            H.y = (unsigned)h4[2] | ((unsigned)h4[3] << 16);
            L.x = (unsigned)l4[0] | ((unsigned)l4[1] << 16);
            L.y = (unsigned)l4[2] | ((unsigned)l4[3] << 16);
            *reinterpret_cast<uint2*>(&Ah[arow][akseg]) = H;
            *reinterpret_cast<uint2*>(&Al[arow][akseg]) = L;

            const float* wp = WselB + obr * 512 + k0 + bkseg;
            unsigned short hh[16], ll[16];
            #pragma unroll
            for (int c = 0; c < 4; ++c) {
                const float4 v = *reinterpret_cast<const float4*>(wp + c * 4);
                cvt_hilo(v.x, hh[c*4+0], ll[c*4+0]);
                cvt_hilo(v.y, hh[c*4+1], ll[c*4+1]);
                cvt_hilo(v.z, hh[c*4+2], ll[c*4+2]);
                cvt_hilo(v.w, hh[c*4+3], ll[c*4+3]);
            }
            *reinterpret_cast<uint4*>(&Bh[brow][bkseg])     = pack8(hh);
            *reinterpret_cast<uint4*>(&Bh[brow][bkseg + 8]) = pack8(hh + 8);
            *reinterpret_cast<uint4*>(&Bl[brow][bkseg])     = pack8(ll);
            *reinterpret_cast<uint4*>(&Bl[brow][bkseg + 8]) = pack8(ll + 8);
        }
        __syncthreads();

        #pragma unroll
        for (int ks = 0; ks < 2; ++ks) {
            const int kb = ks * 32 + fk;
            const short8 ah  = *reinterpret_cast<const short8*>(&Ah[fr][kb]);
            const short8 al_ = *reinterpret_cast<const short8*>(&Al[fr][kb]);
            const short8 bh  = *reinterpret_cast<const short8*>(&Bh[wc + fr][kb]);
            const short8 bl_ = *reinterpret_cast<const short8*>(&Bl[wc + fr][kb]);
            acc = __builtin_amdgcn_mfma_f32_16x16x32_bf16(ah, bh, acc, 0, 0, 0);
            acc = __builtin_amdgcn_mfma_f32_16x16x32_bf16(ah, bl_, acc, 0, 0, 0);
            acc = __builtin_amdgcn_mfma_f32_16x16x32_bf16(al_, bh, acc, 0, 0, 0);
        }
        __syncthreads();
    }

    #pragma unroll
    for (int r = 0; r < 4; ++r)
        sT[(l >> 4) * 4 + r][wc + fr] = acc[r];
    __syncthreads();

    // ---- FL lift + emission: 32 threads, one (row, head-half) each --------
    if (t < 32) {
        const int m = t >> 1, half = t & 1;
        const int row = m0 + m;
        const int b = row >> 9, tt = row & 511;
        const int which = n0 >> 8;
        const int h = ((n0 & 255) >> 5) + half;
        const int bh2 = b * 8 + h;
        const float* bsel = (which == 0) ? bq : (which == 1 ? bk : bv);

        float ys[32];
        float s2 = 0.f;
        #pragma unroll
        for (int k = 0; k < 32; ++k) {
            ys[k] = sT[m][half * 32 + k] + bsel[h * 32 + k];
            s2 = fmaf(ys[k], ys[k], s2);
        }
        const float rr = __builtin_amdgcn_sqrtf(s2);
        const float rs = fminf(fmaxf(rr, 1e-12f), 18.0f);
        const float e  = __expf(rs);
        const float ei = __builtin_amdgcn_rcpf(e);
        const float ch = 0.5f * (e + ei);
        float sc = 0.5f * (e - ei) / rs;
        if (rs < 1e-3f) sc = fmaf(rs * rs, 1.0f / 6.0f, 1.0f);
        float y0 = ch;
        float mink = -y0 * y0;
        #pragma unroll
        for (int k = 0; k < 32; ++k) { ys[k] *= sc; mink = fmaf(ys[k], ys[k], mink); }
        const float inv = __builtin_amdgcn_rsqf(fmaxf(fabsf(mink), 1e-15f));
        y0 = fabsf(y0 * inv);

        const long rbase = (long)(bh2 * Tq + tt) * 64;
        unsigned short hbuf[64], lbuf[64];
        #pragma unroll
        for (int k = 33; k < 64; ++k) { hbuf[k] = 0; lbuf[k] = 0; }

        if (which == 0) {
            float* qp = Qf + (bh2 * Tq + tt) * QS;
            #pragma unroll
            for (int c = 0; c < 8; ++c) {
                float4 v4;
                v4.x = ys[c*4+0] * inv; v4.y = ys[c*4+1] * inv;
                v4.z = ys[c*4+2] * inv; v4.w = ys[c*4+3] * inv;
                *reinterpret_cast<float4*>(qp + c * 4) = v4;
                cvt_hilo(v4.x, hbuf[c*4+0], lbuf[c*4+0]);
                cvt_hilo(v4.y, hbuf[c*4+1], lbuf[c*4+1]);
                cvt_hilo(v4.z, hbuf[c*4+2], lbuf[c*4+2]);
                cvt_hilo(v4.w, hbuf[c*4+3], lbuf[c*4+3]);
            }
            float4 tail; tail.x = y0; tail.y = 0.f; tail.z = 0.f; tail.w = 0.f;
            *reinterpret_cast<float4*>(qp + 32) = tail;
            cvt_hilo(y0, hbuf[32], lbuf[32]);
            #pragma unroll
            for (int c = 0; c < 8; ++c) {
                *reinterpret_cast<uint4*>(&Qh[rbase + c * 8]) = pack8(hbuf + c * 8);
                *reinterpret_cast<uint4*>(&Ql[rbase + c * 8]) = pack8(lbuf + c * 8);
            }
        } else if (which == 1) {
            #pragma unroll
            for (int k = 0; k < 32; ++k)
                cvt_hilo(-ys[k] * inv, hbuf[k], lbuf[k]);
            cvt_hilo(y0, hbuf[32], lbuf[32]);
            #pragma unroll
            for (int c = 0; c < 8; ++c) {
                *reinterpret_cast<uint4*>(&Kh[rbase + c * 8]) = pack8(hbuf + c * 8);
                *reinterpret_cast<uint4*>(&Kl[rbase + c * 8]) = pack8(lbuf + c * 8);
            }
        } else {
            const long v2b = (long)bh2 * 48 * Tq + tt;
            #pragma unroll
            for (int k = 0; k < 32; ++k) {
                const float v = ys[k] * inv;
                hbuf[k] = cvt_rne(-v);          // Vh: sign-folded, rne
                V2h[v2b + (1 + k) * Tq] = cvt_rne(v);
            }
            hbuf[32] = cvt_rne(y0);
            V2h[v2b] = cvt_rne(y0);
            #pragma unroll
            for (int c = 0; c < 8; ++c)
                *reinterpret_cast<uint4*>(&Vh[rbase + c * 8]) = pack8(hbuf + c * 8);
        }
    }
}

// ---------------- Kernel 2: attention, 512 threads (8 waves) ---------------
// grid (32, 16): 16 rows x 512 cols per block. GEMM1: wave w does 4 c-iters.
// GEMM2: 6 waves (3 a-tiles x 2 k-halves). P5 folds partials.
__global__ __launch_bounds__(512) void attn_mfma_kernel(
    const float* __restrict__ Qf,
    const unsigned short* __restrict__ Qh, const unsigned short* __restrict__ Ql,
    const unsigned short* __restrict__ Kh, const unsigned short* __restrict__ Kl,
    const unsigned short* __restrict__ Vh, const unsigned short* __restrict__ V2h,
    float* __restrict__ Ztan)
{
    __shared__ unsigned short sPh[16][528];
    __shared__ float sSe[8][16];
    __shared__ float sWp[2][16][48];

    const int bh = blockIdx.y;
    const int i0 = blockIdx.x * 16;
    const int t  = threadIdx.x;       // 0..511
    const int l  = t & 63, w = t >> 6; // 8 waves
    const int fr = l & 15, fk = (l >> 4) * 8;

    // A-fragments of Q (same rows for all waves)
    short8 qh[2], ql[2];
    {
        const long qb = (long)(bh * Tq + i0 + fr) * 64;
        #pragma unroll
        for (int ks = 0; ks < 2; ++ks) {
            qh[ks] = *reinterpret_cast<const short8*>(&Qh[qb + ks * 32 + fk]);
            ql[ks] = *reinterpret_cast<const short8*>(&Ql[qb + ks * 32 + fk]);
        }
    }

    // ---- GEMM1 (ip hi/lo) + GEMM1b (al single) + elementwise p ------------
    float seLoc[4] = {0.f, 0.f, 0.f, 0.f};
    #pragma unroll
    for (int c = 0; c < 4; ++c) {
        const int j0 = (w * 4 + c) * 16;
        const long kb = (long)(bh * Tq + j0 + fr) * 64;
        f32x4 aK = (f32x4){0.f, 0.f, 0.f, 0.f};
        f32x4 aV = (f32x4){0.f, 0.f, 0.f, 0.f};
        #pragma unroll
        for (int ks = 0; ks < 2; ++ks) {
            const long o = kb + ks * 32 + fk;
            const short8 bkh = *reinterpret_cast<const short8*>(&Kh[o]);
            const short8 bkl = *reinterpret_cast<const short8*>(&Kl[o]);
            const short8 bvh = *reinterpret_cast<const short8*>(&Vh[o]);
            aK = __builtin_amdgcn_mfma_f32_16x16x32_bf16(qh[ks], bkh, aK, 0, 0, 0);
            aK = __builtin_amdgcn_mfma_f32_16x16x32_bf16(qh[ks], bkl, aK, 0, 0, 0);
            aK = __builtin_amdgcn_mfma_f32_16x16x32_bf16(ql[ks], bkh, aK, 0, 0, 0);
            aV = __builtin_amdgcn_mfma_f32_16x16x32_bf16(qh[ks], bvh, aV, 0, 0, 0);
        }
        #pragma unroll
        for (int r = 0; r < 4; ++r) {
            const int i = (l >> 4) * 4 + r;
            const int j = j0 + fr;
            const float d  = facosh(fmaxf(aK[r], 1.0f + EPSF));
            const float al = fmaxf(aV[r], 1.0f + EPSF);
            const float e  = __expf(-d * d);
            const float p  = e * facosh(al);
            seLoc[r] += e;
            sPh[i][j] = cvt_rne(p);
        }
    }
    #pragma unroll
    for (int r = 0; r < 4; ++r) {
        float v = seLoc[r];
        v += __shfl_xor(v, 1, 64);
        v += __shfl_xor(v, 2, 64);
        v += __shfl_xor(v, 4, 64);
        v += __shfl_xor(v, 8, 64);
        if ((l & 15) == 0) sSe[w][(l >> 4) * 4 + r] = v;
    }
    __syncthreads();

    // ---- GEMM2: W[16][48] = p . V2^T, 6 waves (a-tile x k-half) -----------
    if (w < 6) {
        const int a0  = (w % 3) * 16;
        const int kh2 = w / 3;            // 0/1 k-half
        const long vb = (long)bh * 48 * Tq + (long)(a0 + fr) * Tq;
        f32x4 aW = (f32x4){0.f, 0.f, 0.f, 0.f};
        #pragma unroll 4
        for (int ks = kh2 * 8; ks < kh2 * 8 + 8; ++ks) {
            const int ko = ks * 32 + fk;
            const short8 ph  = *reinterpret_cast<const short8*>(&sPh[fr][ko]);
            const short8 v2h = *reinterpret_cast<const short8*>(&V2h[vb + ko]);
            aW = __builtin_amdgcn_mfma_f32_16x16x32_bf16(ph, v2h, aW, 0, 0, 0);
        }
        #pragma unroll
        for (int r = 0; r < 4; ++r)
            sWp[kh2][(l >> 4) * 4 + r][a0 + fr] = aW[r];
    }
    __syncthreads();

    // ---- P5: S identity, normalize, exp_map, origin log -------------------
    if (t < 16) {
        const int i = t;
        float seT = 0.f;
        #pragma unroll
        for (int ww = 0; ww < 8; ++ww) seT += sSe[ww][i];
        float W[33];
        #pragma unroll
        for (int a = 0; a < 33; ++a) W[a] = sWp[0][i][a] + sWp[1][i][a];
        const float* qrow = Qf + (long)(bh * Tq + i0 + i) * QS;
        const float q0 = qrow[32];
        float dot = 0.f;
        #pragma unroll
        for (int a = 1; a < 33; ++a) dot = fmaf(qrow[a - 1], W[a], dot);
        const float S = q0 * W[0] - dot;
        const float cs = CINV * __builtin_amdgcn_rcpf(seT);
        const float y0 = fmaf(cs, fmaf(S, q0, W[0]), q0);
        float mink = -y0 * y0;
        float yv[32];
        #pragma unroll
        for (int a = 1; a < 33; ++a) {
            const float qa = qrow[a - 1];
            const float ya = fmaf(cs, fmaf(S, qa, W[a]), qa);
            yv[a - 1] = ya;
            mink = fmaf(ya, ya, mink);
        }
        const float inv = __builtin_amdgcn_rsqf(fmaxf(fabsf(mink), 1e-15f));
        const float Y0 = fabsf(y0 * inv);
        const float dist0 = facosh(fmaxf(Y0, 1.0f + EPSF));
        const float coef = dist0 * CINV;
        const int b = bh >> 3, h = bh & 7;
        float* zp = Ztan + ((b * Tq + (i0 + i)) * 264) + h * 33;
        zp[0] = coef * (2.0f * Y0);
        #pragma unroll
        for (int a = 1; a < 33; ++a) zp[a] = coef * (yv[a - 1] * inv);
    }
}

// ---------------- Kernel 3: Z = Ztan(1024x264) @ Wo^T + bo, BK=24 ----------
__global__ __launch_bounds__(256) void out_gemm_kernel(
    const float* __restrict__ Ztan, const float* __restrict__ Wo,
    const float* __restrict__ bo, float* __restrict__ out)
{
    __shared__ float AsT[24][36];
    __shared__ float BsT[24][36];
    const int n0 = blockIdx.x * 32;
    const int m0 = blockIdx.y * 32;
    const int t  = threadIdx.x;
    const int tx = t & 15, ty = t >> 4;
    const int ar = t >> 3, ac = t & 7;

    float acc[2][2];
    acc[0][0] = acc[0][1] = acc[1][0] = acc[1][1] = 0.f;

    for (int k0 = 0; k0 < 264; k0 += 24) {
        #pragma unroll
        for (int s = 0; s < 3; ++s) {
            AsT[ac + s * 8][ar] = Ztan[(m0 + ar) * 264 + k0 + ac + s * 8];
            BsT[ac + s * 8][ar] = Wo[(n0 + ar) * 264 + k0 + ac + s * 8];
        }
        __syncthreads();
        #pragma unroll
        for (int kk = 0; kk < 24; ++kk) {
            const float2 a2 = *reinterpret_cast<const float2*>(&AsT[kk][ty * 2]);
            const float2 b2 = *reinterpret_cast<const float2*>(&BsT[kk][tx * 2]);
            acc[0][0] = fmaf(a2.x, b2.x, acc[0][0]);
            acc[0][1] = fmaf(a2.x, b2.y, acc[0][1]);
            acc[1][0] = fmaf(a2.y, b2.x, acc[1][0]);
            acc[1][1] = fmaf(a2.y, b2.y, acc[1][1]);
        }
        __syncthreads();
    }
    #pragma unroll
    for (int c = 0; c < 2; ++c) {
        const int o = n0 + tx * 2 + c;
        const float bias = bo[o];
        #pragma unroll
        for (int r = 0; r < 2; ++r)
            out[(m0 + ty * 2 + r) * 512 + o] = acc[r][c] + bias;
    }
}

} // namespace

// ---------------------------------------------------------------------------
extern "C" void kernel_launch(void* const* d_in, const int* in_sizes, int n_in,
                              void* d_out, int out_size, void* d_ws, size_t ws_size,
                              hipStream_t stream)
{
    const float* x  = (const float*)d_in[0];
    const float* Wq = (const float*)d_in[1];
    const float* bq = (const float*)d_in[2];
    const float* Wk = (const float*)d_in[3];
    const float* bk = (const float*)d_in[4];
    const float* Wv = (const float*)d_in[5];
    const float* bv = (const float*)d_in[6];
    const float* Wo = (const float*)d_in[7];
    const float* bo = (const float*)d_in[8];
    float* out = (float*)d_out;

    float* ws = (float*)d_ws;
    float* Qf = ws;                                   // 294912
    unsigned short* Qh  = (unsigned short*)(ws + 294912);   // 262144 f each
    unsigned short* Ql  = (unsigned short*)(ws + 557056);
    unsigned short* Kh  = (unsigned short*)(ws + 819200);
    unsigned short* Kl  = (unsigned short*)(ws + 1081344);
    unsigned short* Vh  = (unsigned short*)(ws + 1343488);
    unsigned short* V2h = (unsigned short*)(ws + 1605632);  // 196608 f
    float* Zt = ws + 1802240;                         // 270336

    gemm_qkv_mfma_kernel<<<dim3(12, 64), 256, 0, stream>>>(
        x, Wq, bq, Wk, bk, Wv, bv, Qf, Qh, Ql, Kh, Kl, Vh, V2h);
    attn_mfma_kernel<<<dim3(32, 16), 512, 0, stream>>>(
        Qf, Qh, Ql, Kh, Kl, Vh, V2h, Zt);
    out_gemm_kernel<<<dim3(16, 32), 256, 0, stream>>>(Zt, Wo, bo, out);
}

// Round 21
// 43.144 us; speedup vs baseline: 4.8278x; 1.1418x over previous
//
#include <hip/hip_runtime.h>
#include <math.h>

// ---------------------------------------------------------------------------
// LorentzSelfAttention — MI355X
//
// Degenerate-clamp simplification (verified analytically, passed R1-R20):
//   u_agg_i = C*(W_i + S_i*Q_i),  W_i = sum_j p_ij V_j,  p = exp(-d^2)*dist
//   S_i = -mink(Q_i, W_i)  [R9-verified identity]
//   Y_i = mink_normalize(Q_i + u_agg_i/sum_e), |time|
//   Ztan_i = dist0*C * (2*Y0, Ys)
//
// R21 = R20 + out_gemm converted to MFMA hi/lo (last scalar-f32 LDS GEMM;
// same LDS-issue-bound disease R14 cured in qkv for -14us). 32x32 tiles,
// grid (16,32)=512 blocks, K=264 zero-padded to 5x64 chunks, in-kernel
// f32->bf16 hi/lo staging (R14 pattern), direct C-fragment epilogue + bias.
// qkv + attn kernels R20-verbatim.
// ---------------------------------------------------------------------------

namespace {

constexpr int Tq = 512;
constexpr int QS = 36;            // padded f32 Q row stride

#define EPSF  1e-6f
#define CINV  3.16227766e7f       // 1/sqrt(1e-15)

using short8 = __attribute__((ext_vector_type(8))) short;
using f32x4  = __attribute__((ext_vector_type(4))) float;

__device__ __forceinline__ float facosh(float x) {
    return __logf(x + __builtin_amdgcn_sqrtf(fmaf(x, x, -1.0f)));
}

__device__ __forceinline__ void cvt_hilo(float x, unsigned short& h, unsigned short& l) {
    const unsigned u = __float_as_uint(x);
    h = (unsigned short)(u >> 16);
    const float xh = __uint_as_float(u & 0xFFFF0000u);
    l = (unsigned short)(__float_as_uint(x - xh) >> 16);
}

__device__ __forceinline__ unsigned short cvt_rne(float x) {
    const unsigned u = __float_as_uint(x);
    return (unsigned short)((u + 0x7FFFu + ((u >> 16) & 1u)) >> 16);
}

__device__ __forceinline__ uint4 pack8(const unsigned short* s) {
    uint4 r;
    r.x = (unsigned)s[0] | ((unsigned)s[1] << 16);
    r.y = (unsigned)s[2] | ((unsigned)s[3] << 16);
    r.z = (unsigned)s[4] | ((unsigned)s[5] << 16);
    r.w = (unsigned)s[6] | ((unsigned)s[7] << 16);
    return r;
}

// ---------------- Kernel 1: QKV GEMM, 16x64 tiles, grid (12,64) (R20) ------
__global__ __launch_bounds__(256) void gemm_qkv_mfma_kernel(
    const float* __restrict__ x,
    const float* __restrict__ Wq, const float* __restrict__ bq,
    const float* __restrict__ Wk, const float* __restrict__ bk,
    const float* __restrict__ Wv, const float* __restrict__ bv,
    float* __restrict__ Qf,
    unsigned short* __restrict__ Qh, unsigned short* __restrict__ Ql,
    unsigned short* __restrict__ Kh, unsigned short* __restrict__ Kl,
    unsigned short* __restrict__ Vh, unsigned short* __restrict__ V2h)
{
    __shared__ unsigned short Ah[16][72], Al[16][72];
    __shared__ unsigned short Bh[64][72], Bl[64][72];
    __shared__ float sT[16][65];

    const int n0 = blockIdx.x * 64;
    const int m0 = blockIdx.y * 16;
    const int t  = threadIdx.x;
    const int l  = t & 63, w = t >> 6;
    const int wc = w * 16;
    const int fr = l & 15, fk = (l >> 4) * 8;

    const int arow = t >> 4, akseg = (t & 15) * 4;
    const int brow = t >> 2, bkseg = (t & 3) * 16;
    const int ob  = n0 + brow;
    const float* WselB = (ob < 256) ? Wq : (ob < 512 ? Wk : Wv);
    const int obr = ob & 255;

    f32x4 acc = (f32x4){0.f, 0.f, 0.f, 0.f};

    for (int k0 = 0; k0 < 512; k0 += 64) {
        {
            const float4 av = *reinterpret_cast<const float4*>(
                &x[(m0 + arow) * 512 + k0 + akseg]);
            unsigned short h4[4], l4[4];
            cvt_hilo(av.x, h4[0], l4[0]); cvt_hilo(av.y, h4[1], l4[1]);
            cvt_hilo(av.z, h4[2], l4[2]); cvt_hilo(av.w, h4[3], l4[3]);
            uint2 H, L;
            H.x = (unsigned)h4[0] | ((unsigned)h4[1] << 16);
            H.y = (unsigned)h4[2] | ((unsigned)h4[3] << 16);
            L.x = (unsigned)l4[0] | ((unsigned)l4[1] << 16);
            L.y = (unsigned)l4[2] | ((unsigned)l4[3] << 16);
            *reinterpret_cast<uint2*>(&Ah[arow][akseg]) = H;
            *reinterpret_cast<uint2*>(&Al[arow][akseg]) = L;

            const float* wp = WselB + obr * 512 + k0 + bkseg;
            unsigned short hh[16], ll[16];
            #pragma unroll
            for (int c = 0; c < 4; ++c) {
                const float4 v = *reinterpret_cast<const float4*>(wp + c * 4);
                cvt_hilo(v.x, hh[c*4+0], ll[c*4+0]);
                cvt_hilo(v.y, hh[c*4+1], ll[c*4+1]);
                cvt_hilo(v.z, hh[c*4+2], ll[c*4+2]);
                cvt_hilo(v.w, hh[c*4+3], ll[c*4+3]);
            }
            *reinterpret_cast<uint4*>(&Bh[brow][bkseg])     = pack8(hh);
            *reinterpret_cast<uint4*>(&Bh[brow][bkseg + 8]) = pack8(hh + 8);
            *reinterpret_cast<uint4*>(&Bl[brow][bkseg])     = pack8(ll);
            *reinterpret_cast<uint4*>(&Bl[brow][bkseg + 8]) = pack8(ll + 8);
        }
        __syncthreads();

        #pragma unroll
        for (int ks = 0; ks < 2; ++ks) {
            const int kb = ks * 32 + fk;
            const short8 ah  = *reinterpret_cast<const short8*>(&Ah[fr][kb]);
            const short8 al_ = *reinterpret_cast<const short8*>(&Al[fr][kb]);
            const short8 bh  = *reinterpret_cast<const short8*>(&Bh[wc + fr][kb]);
            const short8 bl_ = *reinterpret_cast<const short8*>(&Bl[wc + fr][kb]);
            acc = __builtin_amdgcn_mfma_f32_16x16x32_bf16(ah, bh, acc, 0, 0, 0);
            acc = __builtin_amdgcn_mfma_f32_16x16x32_bf16(ah, bl_, acc, 0, 0, 0);
            acc = __builtin_amdgcn_mfma_f32_16x16x32_bf16(al_, bh, acc, 0, 0, 0);
        }
        __syncthreads();
    }

    #pragma unroll
    for (int r = 0; r < 4; ++r)
        sT[(l >> 4) * 4 + r][wc + fr] = acc[r];
    __syncthreads();

    if (t < 32) {
        const int m = t >> 1, half = t & 1;
        const int row = m0 + m;
        const int b = row >> 9, tt = row & 511;
        const int which = n0 >> 8;
        const int h = ((n0 & 255) >> 5) + half;
        const int bh2 = b * 8 + h;
        const float* bsel = (which == 0) ? bq : (which == 1 ? bk : bv);

        float ys[32];
        float s2 = 0.f;
        #pragma unroll
        for (int k = 0; k < 32; ++k) {
            ys[k] = sT[m][half * 32 + k] + bsel[h * 32 + k];
            s2 = fmaf(ys[k], ys[k], s2);
        }
        const float rr = __builtin_amdgcn_sqrtf(s2);
        const float rs = fminf(fmaxf(rr, 1e-12f), 18.0f);
        const float e  = __expf(rs);
        const float ei = __builtin_amdgcn_rcpf(e);
        const float ch = 0.5f * (e + ei);
        float sc = 0.5f * (e - ei) / rs;
        if (rs < 1e-3f) sc = fmaf(rs * rs, 1.0f / 6.0f, 1.0f);
        float y0 = ch;
        float mink = -y0 * y0;
        #pragma unroll
        for (int k = 0; k < 32; ++k) { ys[k] *= sc; mink = fmaf(ys[k], ys[k], mink); }
        const float inv = __builtin_amdgcn_rsqf(fmaxf(fabsf(mink), 1e-15f));
        y0 = fabsf(y0 * inv);

        const long rbase = (long)(bh2 * Tq + tt) * 64;
        unsigned short hbuf[64], lbuf[64];
        #pragma unroll
        for (int k = 33; k < 64; ++k) { hbuf[k] = 0; lbuf[k] = 0; }

        if (which == 0) {
            float* qp = Qf + (bh2 * Tq + tt) * QS;
            #pragma unroll
            for (int c = 0; c < 8; ++c) {
                float4 v4;
                v4.x = ys[c*4+0] * inv; v4.y = ys[c*4+1] * inv;
                v4.z = ys[c*4+2] * inv; v4.w = ys[c*4+3] * inv;
                *reinterpret_cast<float4*>(qp + c * 4) = v4;
                cvt_hilo(v4.x, hbuf[c*4+0], lbuf[c*4+0]);
                cvt_hilo(v4.y, hbuf[c*4+1], lbuf[c*4+1]);
                cvt_hilo(v4.z, hbuf[c*4+2], lbuf[c*4+2]);
                cvt_hilo(v4.w, hbuf[c*4+3], lbuf[c*4+3]);
            }
            float4 tail; tail.x = y0; tail.y = 0.f; tail.z = 0.f; tail.w = 0.f;
            *reinterpret_cast<float4*>(qp + 32) = tail;
            cvt_hilo(y0, hbuf[32], lbuf[32]);
            #pragma unroll
            for (int c = 0; c < 8; ++c) {
                *reinterpret_cast<uint4*>(&Qh[rbase + c * 8]) = pack8(hbuf + c * 8);
                *reinterpret_cast<uint4*>(&Ql[rbase + c * 8]) = pack8(lbuf + c * 8);
            }
        } else if (which == 1) {
            #pragma unroll
            for (int k = 0; k < 32; ++k)
                cvt_hilo(-ys[k] * inv, hbuf[k], lbuf[k]);
            cvt_hilo(y0, hbuf[32], lbuf[32]);
            #pragma unroll
            for (int c = 0; c < 8; ++c) {
                *reinterpret_cast<uint4*>(&Kh[rbase + c * 8]) = pack8(hbuf + c * 8);
                *reinterpret_cast<uint4*>(&Kl[rbase + c * 8]) = pack8(lbuf + c * 8);
            }
        } else {
            const long v2b = (long)bh2 * 48 * Tq + tt;
            #pragma unroll
            for (int k = 0; k < 32; ++k) {
                const float v = ys[k] * inv;
                hbuf[k] = cvt_rne(-v);
                V2h[v2b + (1 + k) * Tq] = cvt_rne(v);
            }
            hbuf[32] = cvt_rne(y0);
            V2h[v2b] = cvt_rne(y0);
            #pragma unroll
            for (int c = 0; c < 8; ++c)
                *reinterpret_cast<uint4*>(&Vh[rbase + c * 8]) = pack8(hbuf + c * 8);
        }
    }
}

// ---------------- Kernel 2: attention, 512 threads (8 waves) (R20) ---------
__global__ __launch_bounds__(512) void attn_mfma_kernel(
    const float* __restrict__ Qf,
    const unsigned short* __restrict__ Qh, const unsigned short* __restrict__ Ql,
    const unsigned short* __restrict__ Kh, const unsigned short* __restrict__ Kl,
    const unsigned short* __restrict__ Vh, const unsigned short* __restrict__ V2h,
    float* __restrict__ Ztan)
{
    __shared__ unsigned short sPh[16][528];
    __shared__ float sSe[8][16];
    __shared__ float sWp[2][16][48];

    const int bh = blockIdx.y;
    const int i0 = blockIdx.x * 16;
    const int t  = threadIdx.x;
    const int l  = t & 63, w = t >> 6;
    const int fr = l & 15, fk = (l >> 4) * 8;

    short8 qh[2], ql[2];
    {
        const long qb = (long)(bh * Tq + i0 + fr) * 64;
        #pragma unroll
        for (int ks = 0; ks < 2; ++ks) {
            qh[ks] = *reinterpret_cast<const short8*>(&Qh[qb + ks * 32 + fk]);
            ql[ks] = *reinterpret_cast<const short8*>(&Ql[qb + ks * 32 + fk]);
        }
    }

    float seLoc[4] = {0.f, 0.f, 0.f, 0.f};
    #pragma unroll
    for (int c = 0; c < 4; ++c) {
        const int j0 = (w * 4 + c) * 16;
        const long kb = (long)(bh * Tq + j0 + fr) * 64;
        f32x4 aK = (f32x4){0.f, 0.f, 0.f, 0.f};
        f32x4 aV = (f32x4){0.f, 0.f, 0.f, 0.f};
        #pragma unroll
        for (int ks = 0; ks < 2; ++ks) {
            const long o = kb + ks * 32 + fk;
            const short8 bkh = *reinterpret_cast<const short8*>(&Kh[o]);
            const short8 bkl = *reinterpret_cast<const short8*>(&Kl[o]);
            const short8 bvh = *reinterpret_cast<const short8*>(&Vh[o]);
            aK = __builtin_amdgcn_mfma_f32_16x16x32_bf16(qh[ks], bkh, aK, 0, 0, 0);
            aK = __builtin_amdgcn_mfma_f32_16x16x32_bf16(qh[ks], bkl, aK, 0, 0, 0);
            aK = __builtin_amdgcn_mfma_f32_16x16x32_bf16(ql[ks], bkh, aK, 0, 0, 0);
            aV = __builtin_amdgcn_mfma_f32_16x16x32_bf16(qh[ks], bvh, aV, 0, 0, 0);
        }
        #pragma unroll
        for (int r = 0; r < 4; ++r) {
            const int i = (l >> 4) * 4 + r;
            const int j = j0 + fr;
            const float d  = facosh(fmaxf(aK[r], 1.0f + EPSF));
            const float al = fmaxf(aV[r], 1.0f + EPSF);
            const float e  = __expf(-d * d);
            const float p  = e * facosh(al);
            seLoc[r] += e;
            sPh[i][j] = cvt_rne(p);
        }
    }
    #pragma unroll
    for (int r = 0; r < 4; ++r) {
        float v = seLoc[r];
        v += __shfl_xor(v, 1, 64);
        v += __shfl_xor(v, 2, 64);
        v += __shfl_xor(v, 4, 64);
        v += __shfl_xor(v, 8, 64);
        if ((l & 15) == 0) sSe[w][(l >> 4) * 4 + r] = v;
    }
    __syncthreads();

    if (w < 6) {
        const int a0  = (w % 3) * 16;
        const int kh2 = w / 3;
        const long vb = (long)bh * 48 * Tq + (long)(a0 + fr) * Tq;
        f32x4 aW = (f32x4){0.f, 0.f, 0.f, 0.f};
        #pragma unroll 4
        for (int ks = kh2 * 8; ks < kh2 * 8 + 8; ++ks) {
            const int ko = ks * 32 + fk;
            const short8 ph  = *reinterpret_cast<const short8*>(&sPh[fr][ko]);
            const short8 v2h = *reinterpret_cast<const short8*>(&V2h[vb + ko]);
            aW = __builtin_amdgcn_mfma_f32_16x16x32_bf16(ph, v2h, aW, 0, 0, 0);
        }
        #pragma unroll
        for (int r = 0; r < 4; ++r)
            sWp[kh2][(l >> 4) * 4 + r][a0 + fr] = aW[r];
    }
    __syncthreads();

    if (t < 16) {
        const int i = t;
        float seT = 0.f;
        #pragma unroll
        for (int ww = 0; ww < 8; ++ww) seT += sSe[ww][i];
        float W[33];
        #pragma unroll
        for (int a = 0; a < 33; ++a) W[a] = sWp[0][i][a] + sWp[1][i][a];
        const float* qrow = Qf + (long)(bh * Tq + i0 + i) * QS;
        const float q0 = qrow[32];
        float dot = 0.f;
        #pragma unroll
        for (int a = 1; a < 33; ++a) dot = fmaf(qrow[a - 1], W[a], dot);
        const float S = q0 * W[0] - dot;
        const float cs = CINV * __builtin_amdgcn_rcpf(seT);
        const float y0 = fmaf(cs, fmaf(S, q0, W[0]), q0);
        float mink = -y0 * y0;
        float yv[32];
        #pragma unroll
        for (int a = 1; a < 33; ++a) {
            const float qa = qrow[a - 1];
            const float ya = fmaf(cs, fmaf(S, qa, W[a]), qa);
            yv[a - 1] = ya;
            mink = fmaf(ya, ya, mink);
        }
        const float inv = __builtin_amdgcn_rsqf(fmaxf(fabsf(mink), 1e-15f));
        const float Y0 = fabsf(y0 * inv);
        const float dist0 = facosh(fmaxf(Y0, 1.0f + EPSF));
        const float coef = dist0 * CINV;
        const int b = bh >> 3, h = bh & 7;
        float* zp = Ztan + ((b * Tq + (i0 + i)) * 264) + h * 33;
        zp[0] = coef * (2.0f * Y0);
        #pragma unroll
        for (int a = 1; a < 33; ++a) zp[a] = coef * (yv[a - 1] * inv);
    }
}

// ---------------- Kernel 3: out GEMM via MFMA hi/lo, 32x32, grid (16,32) ---
// out[1024][512] = Ztan[1024][264] @ Wo^T + bo. K padded to 5x64 (zeros).
__global__ __launch_bounds__(256) void out_gemm_mfma_kernel(
    const float* __restrict__ Ztan, const float* __restrict__ Wo,
    const float* __restrict__ bo, float* __restrict__ out)
{
    __shared__ unsigned short Ah[32][72], Al[32][72];
    __shared__ unsigned short Bh[32][72], Bl[32][72];

    const int n0 = blockIdx.x * 32;
    const int m0 = blockIdx.y * 32;
    const int t  = threadIdx.x;
    const int l  = t & 63, w = t >> 6;
    const int wr = (w >> 1) * 16, wc = (w & 1) * 16;
    const int fr = l & 15, fk = (l >> 4) * 8;

    // staging: 32 rows x 64 k, 8 elems/thread
    const int sr = t >> 3, sk = (t & 7) * 8;

    f32x4 acc = (f32x4){0.f, 0.f, 0.f, 0.f};

    for (int k0 = 0; k0 < 264; k0 += 64) {
        const bool full = (k0 + sk + 7 < 264);
        {
            unsigned short h8[8], l8[8];
            if (full) {
                const float4 a0v = *reinterpret_cast<const float4*>(
                    &Ztan[(m0 + sr) * 264 + k0 + sk]);
                const float4 a1v = *reinterpret_cast<const float4*>(
                    &Ztan[(m0 + sr) * 264 + k0 + sk + 4]);
                cvt_hilo(a0v.x, h8[0], l8[0]); cvt_hilo(a0v.y, h8[1], l8[1]);
                cvt_hilo(a0v.z, h8[2], l8[2]); cvt_hilo(a0v.w, h8[3], l8[3]);
                cvt_hilo(a1v.x, h8[4], l8[4]); cvt_hilo(a1v.y, h8[5], l8[5]);
                cvt_hilo(a1v.z, h8[6], l8[6]); cvt_hilo(a1v.w, h8[7], l8[7]);
            } else {
                #pragma unroll
                for (int c = 0; c < 8; ++c) { h8[c] = 0; l8[c] = 0; }
            }
            *reinterpret_cast<uint4*>(&Ah[sr][sk]) = pack8(h8);
            *reinterpret_cast<uint4*>(&Al[sr][sk]) = pack8(l8);

            if (full) {
                const float4 b0v = *reinterpret_cast<const float4*>(
                    &Wo[(n0 + sr) * 264 + k0 + sk]);
                const float4 b1v = *reinterpret_cast<const float4*>(
                    &Wo[(n0 + sr) * 264 + k0 + sk + 4]);
                cvt_hilo(b0v.x, h8[0], l8[0]); cvt_hilo(b0v.y, h8[1], l8[1]);
                cvt_hilo(b0v.z, h8[2], l8[2]); cvt_hilo(b0v.w, h8[3], l8[3]);
                cvt_hilo(b1v.x, h8[4], l8[4]); cvt_hilo(b1v.y, h8[5], l8[5]);
                cvt_hilo(b1v.z, h8[6], l8[6]); cvt_hilo(b1v.w, h8[7], l8[7]);
            } else {
                #pragma unroll
                for (int c = 0; c < 8; ++c) { h8[c] = 0; l8[c] = 0; }
            }
            *reinterpret_cast<uint4*>(&Bh[sr][sk]) = pack8(h8);
            *reinterpret_cast<uint4*>(&Bl[sr][sk]) = pack8(l8);
        }
        __syncthreads();

        #pragma unroll
        for (int ks = 0; ks < 2; ++ks) {
            const int kb = ks * 32 + fk;
            const short8 ah  = *reinterpret_cast<const short8*>(&Ah[wr + fr][kb]);
            const short8 al_ = *reinterpret_cast<const short8*>(&Al[wr + fr][kb]);
            const short8 bh  = *reinterpret_cast<const short8*>(&Bh[wc + fr][kb]);
            const short8 bl_ = *reinterpret_cast<const short8*>(&Bl[wc + fr][kb]);
            acc = __builtin_amdgcn_mfma_f32_16x16x32_bf16(ah, bh, acc, 0, 0, 0);
            acc = __builtin_amdgcn_mfma_f32_16x16x32_bf16(ah, bl_, acc, 0, 0, 0);
            acc = __builtin_amdgcn_mfma_f32_16x16x32_bf16(al_, bh, acc, 0, 0, 0);
        }
        __syncthreads();
    }

    // epilogue: C layout col = l&15, row = (l>>4)*4 + r; bias + store
    const int col = n0 + wc + fr;
    const float bias = bo[col];
    #pragma unroll
    for (int r = 0; r < 4; ++r) {
        const int row = m0 + wr + (l >> 4) * 4 + r;
        out[row * 512 + col] = acc[r] + bias;
    }
}

} // namespace

// ---------------------------------------------------------------------------
extern "C" void kernel_launch(void* const* d_in, const int* in_sizes, int n_in,
                              void* d_out, int out_size, void* d_ws, size_t ws_size,
                              hipStream_t stream)
{
    const float* x  = (const float*)d_in[0];
    const float* Wq = (const float*)d_in[1];
    const float* bq = (const float*)d_in[2];
    const float* Wk = (const float*)d_in[3];
    const float* bk = (const float*)d_in[4];
    const float* Wv = (const float*)d_in[5];
    const float* bv = (const float*)d_in[6];
    const float* Wo = (const float*)d_in[7];
    const float* bo = (const float*)d_in[8];
    float* out = (float*)d_out;

    float* ws = (float*)d_ws;
    float* Qf = ws;                                   // 294912
    unsigned short* Qh  = (unsigned short*)(ws + 294912);
    unsigned short* Ql  = (unsigned short*)(ws + 557056);
    unsigned short* Kh  = (unsigned short*)(ws + 819200);
    unsigned short* Kl  = (unsigned short*)(ws + 1081344);
    unsigned short* Vh  = (unsigned short*)(ws + 1343488);
    unsigned short* V2h = (unsigned short*)(ws + 1605632);
    float* Zt = ws + 1802240;                         // 270336

    gemm_qkv_mfma_kernel<<<dim3(12, 64), 256, 0, stream>>>(
        x, Wq, bq, Wk, bk, Wv, bv, Qf, Qh, Ql, Kh, Kl, Vh, V2h);
    attn_mfma_kernel<<<dim3(32, 16), 512, 0, stream>>>(
        Qf, Qh, Ql, Kh, Kl, Vh, V2h, Zt);
    out_gemm_mfma_kernel<<<dim3(16, 32), 256, 0, stream>>>(Zt, Wo, bo, out);
}

// Round 22
// 41.104 us; speedup vs baseline: 5.0674x; 1.0496x over previous
//
#include <hip/hip_runtime.h>
#include <math.h>

// ---------------------------------------------------------------------------
// LorentzSelfAttention — MI355X
//
// Degenerate-clamp simplification (verified analytically, passed R1-R21):
//   u_agg_i = C*(W_i + S_i*Q_i),  W_i = sum_j p_ij V_j,  p = exp(-d^2)*dist
//   S_i = -mink(Q_i, W_i)  [R9-verified identity]
//   Y_i = mink_normalize(Q_i + u_agg_i/sum_e), |time|
//   Ztan_i = dist0*C * (2*Y0, Ys)
//
// R22 = R21 + (1) K single bf16-RNE (Kl stream dropped: GEMM1 3->2 mfma,
// -25% attn panel traffic; error budget: absmax 1.05e6 -> ~2-3e6 vs 5.75e6
// threshold, revert if exceeded) + (2) XCD-aware block swizzle in attn/qkv
// (panel-sharing blocks pinned to one XCD's L2; bijective remaps 512=8x64,
// 768=8x96). out_gemm R21-verbatim.
// ---------------------------------------------------------------------------

namespace {

constexpr int Tq = 512;
constexpr int QS = 36;            // padded f32 Q row stride

#define EPSF  1e-6f
#define CINV  3.16227766e7f       // 1/sqrt(1e-15)

using short8 = __attribute__((ext_vector_type(8))) short;
using f32x4  = __attribute__((ext_vector_type(4))) float;

__device__ __forceinline__ float facosh(float x) {
    return __logf(x + __builtin_amdgcn_sqrtf(fmaf(x, x, -1.0f)));
}

__device__ __forceinline__ void cvt_hilo(float x, unsigned short& h, unsigned short& l) {
    const unsigned u = __float_as_uint(x);
    h = (unsigned short)(u >> 16);
    const float xh = __uint_as_float(u & 0xFFFF0000u);
    l = (unsigned short)(__float_as_uint(x - xh) >> 16);
}

__device__ __forceinline__ unsigned short cvt_rne(float x) {
    const unsigned u = __float_as_uint(x);
    return (unsigned short)((u + 0x7FFFu + ((u >> 16) & 1u)) >> 16);
}

__device__ __forceinline__ uint4 pack8(const unsigned short* s) {
    uint4 r;
    r.x = (unsigned)s[0] | ((unsigned)s[1] << 16);
    r.y = (unsigned)s[2] | ((unsigned)s[3] << 16);
    r.z = (unsigned)s[4] | ((unsigned)s[5] << 16);
    r.w = (unsigned)s[6] | ((unsigned)s[7] << 16);
    return r;
}

// ---------------- Kernel 1: QKV GEMM, 16x64 tiles, 768 blocks --------------
__global__ __launch_bounds__(256) void gemm_qkv_mfma_kernel(
    const float* __restrict__ x,
    const float* __restrict__ Wq, const float* __restrict__ bq,
    const float* __restrict__ Wk, const float* __restrict__ bk,
    const float* __restrict__ Wv, const float* __restrict__ bv,
    float* __restrict__ Qf,
    unsigned short* __restrict__ Qh, unsigned short* __restrict__ Ql,
    unsigned short* __restrict__ Kh,
    unsigned short* __restrict__ Vh, unsigned short* __restrict__ V2h)
{
    __shared__ unsigned short Ah[16][72], Al[16][72];
    __shared__ unsigned short Bh[64][72], Bl[64][72];
    __shared__ float sT[16][65];

    // XCD swizzle: 768 = 8 * 96; same-n0 blocks cluster on one XCD
    const int bid = blockIdx.y * 12 + blockIdx.x;
    const int swz = (bid & 7) * 96 + (bid >> 3);
    const int n0 = (swz >> 6) * 64;       // 12 feature blocks
    const int m0 = (swz & 63) * 16;       // 64 row blocks

    const int t  = threadIdx.x;
    const int l  = t & 63, w = t >> 6;
    const int wc = w * 16;
    const int fr = l & 15, fk = (l >> 4) * 8;

    const int arow = t >> 4, akseg = (t & 15) * 4;
    const int brow = t >> 2, bkseg = (t & 3) * 16;
    const int ob  = n0 + brow;
    const float* WselB = (ob < 256) ? Wq : (ob < 512 ? Wk : Wv);
    const int obr = ob & 255;

    f32x4 acc = (f32x4){0.f, 0.f, 0.f, 0.f};

    for (int k0 = 0; k0 < 512; k0 += 64) {
        {
            const float4 av = *reinterpret_cast<const float4*>(
                &x[(m0 + arow) * 512 + k0 + akseg]);
            unsigned short h4[4], l4[4];
            cvt_hilo(av.x, h4[0], l4[0]); cvt_hilo(av.y, h4[1], l4[1]);
            cvt_hilo(av.z, h4[2], l4[2]); cvt_hilo(av.w, h4[3], l4[3]);
            uint2 H, L;
            H.x = (unsigned)h4[0] | ((unsigned)h4[1] << 16);
            H.y = (unsigned)h4[2] | ((unsigned)h4[3] << 16);
            L.x = (unsigned)l4[0] | ((unsigned)l4[1] << 16);
            L.y = (unsigned)l4[2] | ((unsigned)l4[3] << 16);
            *reinterpret_cast<uint2*>(&Ah[arow][akseg]) = H;
            *reinterpret_cast<uint2*>(&Al[arow][akseg]) = L;

            const float* wp = WselB + obr * 512 + k0 + bkseg;
            unsigned short hh[16], ll[16];
            #pragma unroll
            for (int c = 0; c < 4; ++c) {
                const float4 v = *reinterpret_cast<const float4*>(wp + c * 4);
                cvt_hilo(v.x, hh[c*4+0], ll[c*4+0]);
                cvt_hilo(v.y, hh[c*4+1], ll[c*4+1]);
                cvt_hilo(v.z, hh[c*4+2], ll[c*4+2]);
                cvt_hilo(v.w, hh[c*4+3], ll[c*4+3]);
            }
            *reinterpret_cast<uint4*>(&Bh[brow][bkseg])     = pack8(hh);
            *reinterpret_cast<uint4*>(&Bh[brow][bkseg + 8]) = pack8(hh + 8);
            *reinterpret_cast<uint4*>(&Bl[brow][bkseg])     = pack8(ll);
            *reinterpret_cast<uint4*>(&Bl[brow][bkseg + 8]) = pack8(ll + 8);
        }
        __syncthreads();

        #pragma unroll
        for (int ks = 0; ks < 2; ++ks) {
            const int kb = ks * 32 + fk;
            const short8 ah  = *reinterpret_cast<const short8*>(&Ah[fr][kb]);
            const short8 al_ = *reinterpret_cast<const short8*>(&Al[fr][kb]);
            const short8 bh  = *reinterpret_cast<const short8*>(&Bh[wc + fr][kb]);
            const short8 bl_ = *reinterpret_cast<const short8*>(&Bl[wc + fr][kb]);
            acc = __builtin_amdgcn_mfma_f32_16x16x32_bf16(ah, bh, acc, 0, 0, 0);
            acc = __builtin_amdgcn_mfma_f32_16x16x32_bf16(ah, bl_, acc, 0, 0, 0);
            acc = __builtin_amdgcn_mfma_f32_16x16x32_bf16(al_, bh, acc, 0, 0, 0);
        }
        __syncthreads();
    }

    #pragma unroll
    for (int r = 0; r < 4; ++r)
        sT[(l >> 4) * 4 + r][wc + fr] = acc[r];
    __syncthreads();

    if (t < 32) {
        const int m = t >> 1, half = t & 1;
        const int row = m0 + m;
        const int b = row >> 9, tt = row & 511;
        const int which = n0 >> 8;
        const int h = ((n0 & 255) >> 5) + half;
        const int bh2 = b * 8 + h;
        const float* bsel = (which == 0) ? bq : (which == 1 ? bk : bv);

        float ys[32];
        float s2 = 0.f;
        #pragma unroll
        for (int k = 0; k < 32; ++k) {
            ys[k] = sT[m][half * 32 + k] + bsel[h * 32 + k];
            s2 = fmaf(ys[k], ys[k], s2);
        }
        const float rr = __builtin_amdgcn_sqrtf(s2);
        const float rs = fminf(fmaxf(rr, 1e-12f), 18.0f);
        const float e  = __expf(rs);
        const float ei = __builtin_amdgcn_rcpf(e);
        const float ch = 0.5f * (e + ei);
        float sc = 0.5f * (e - ei) / rs;
        if (rs < 1e-3f) sc = fmaf(rs * rs, 1.0f / 6.0f, 1.0f);
        float y0 = ch;
        float mink = -y0 * y0;
        #pragma unroll
        for (int k = 0; k < 32; ++k) { ys[k] *= sc; mink = fmaf(ys[k], ys[k], mink); }
        const float inv = __builtin_amdgcn_rsqf(fmaxf(fabsf(mink), 1e-15f));
        y0 = fabsf(y0 * inv);

        const long rbase = (long)(bh2 * Tq + tt) * 64;
        unsigned short hbuf[64], lbuf[64];
        #pragma unroll
        for (int k = 33; k < 64; ++k) { hbuf[k] = 0; lbuf[k] = 0; }

        if (which == 0) {
            float* qp = Qf + (bh2 * Tq + tt) * QS;
            #pragma unroll
            for (int c = 0; c < 8; ++c) {
                float4 v4;
                v4.x = ys[c*4+0] * inv; v4.y = ys[c*4+1] * inv;
                v4.z = ys[c*4+2] * inv; v4.w = ys[c*4+3] * inv;
                *reinterpret_cast<float4*>(qp + c * 4) = v4;
                cvt_hilo(v4.x, hbuf[c*4+0], lbuf[c*4+0]);
                cvt_hilo(v4.y, hbuf[c*4+1], lbuf[c*4+1]);
                cvt_hilo(v4.z, hbuf[c*4+2], lbuf[c*4+2]);
                cvt_hilo(v4.w, hbuf[c*4+3], lbuf[c*4+3]);
            }
            float4 tail; tail.x = y0; tail.y = 0.f; tail.z = 0.f; tail.w = 0.f;
            *reinterpret_cast<float4*>(qp + 32) = tail;
            cvt_hilo(y0, hbuf[32], lbuf[32]);
            #pragma unroll
            for (int c = 0; c < 8; ++c) {
                *reinterpret_cast<uint4*>(&Qh[rbase + c * 8]) = pack8(hbuf + c * 8);
                *reinterpret_cast<uint4*>(&Ql[rbase + c * 8]) = pack8(lbuf + c * 8);
            }
        } else if (which == 1) {
            // K: single bf16-RNE, sign folded
            #pragma unroll
            for (int k = 0; k < 32; ++k)
                hbuf[k] = cvt_rne(-ys[k] * inv);
            hbuf[32] = cvt_rne(y0);
            #pragma unroll
            for (int c = 0; c < 8; ++c)
                *reinterpret_cast<uint4*>(&Kh[rbase + c * 8]) = pack8(hbuf + c * 8);
        } else {
            const long v2b = (long)bh2 * 48 * Tq + tt;
            #pragma unroll
            for (int k = 0; k < 32; ++k) {
                const float v = ys[k] * inv;
                hbuf[k] = cvt_rne(-v);
                V2h[v2b + (1 + k) * Tq] = cvt_rne(v);
            }
            hbuf[32] = cvt_rne(y0);
            V2h[v2b] = cvt_rne(y0);
            #pragma unroll
            for (int c = 0; c < 8; ++c)
                *reinterpret_cast<uint4*>(&Vh[rbase + c * 8]) = pack8(hbuf + c * 8);
        }
    }
}

// ---------------- Kernel 2: attention, 512 threads, XCD-swizzled -----------
__global__ __launch_bounds__(512) void attn_mfma_kernel(
    const float* __restrict__ Qf,
    const unsigned short* __restrict__ Qh, const unsigned short* __restrict__ Ql,
    const unsigned short* __restrict__ Kh,
    const unsigned short* __restrict__ Vh, const unsigned short* __restrict__ V2h,
    float* __restrict__ Ztan)
{
    __shared__ unsigned short sPh[16][528];
    __shared__ float sSe[8][16];
    __shared__ float sWp[2][16][48];

    // XCD swizzle: 512 = 8 * 64; each XCD covers 2 full bh panels
    const int bid = blockIdx.y * 32 + blockIdx.x;
    const int swz = (bid & 7) * 64 + (bid >> 3);
    const int bh = swz >> 5;
    const int i0 = (swz & 31) * 16;

    const int t  = threadIdx.x;
    const int l  = t & 63, w = t >> 6;
    const int fr = l & 15, fk = (l >> 4) * 8;

    short8 qh[2], ql[2];
    {
        const long qb = (long)(bh * Tq + i0 + fr) * 64;
        #pragma unroll
        for (int ks = 0; ks < 2; ++ks) {
            qh[ks] = *reinterpret_cast<const short8*>(&Qh[qb + ks * 32 + fk]);
            ql[ks] = *reinterpret_cast<const short8*>(&Ql[qb + ks * 32 + fk]);
        }
    }

    float seLoc[4] = {0.f, 0.f, 0.f, 0.f};
    #pragma unroll
    for (int c = 0; c < 4; ++c) {
        const int j0 = (w * 4 + c) * 16;
        const long kb = (long)(bh * Tq + j0 + fr) * 64;
        f32x4 aK = (f32x4){0.f, 0.f, 0.f, 0.f};
        f32x4 aV = (f32x4){0.f, 0.f, 0.f, 0.f};
        #pragma unroll
        for (int ks = 0; ks < 2; ++ks) {
            const long o = kb + ks * 32 + fk;
            const short8 bkh = *reinterpret_cast<const short8*>(&Kh[o]);
            const short8 bvh = *reinterpret_cast<const short8*>(&Vh[o]);
            aK = __builtin_amdgcn_mfma_f32_16x16x32_bf16(qh[ks], bkh, aK, 0, 0, 0);
            aK = __builtin_amdgcn_mfma_f32_16x16x32_bf16(ql[ks], bkh, aK, 0, 0, 0);
            aV = __builtin_amdgcn_mfma_f32_16x16x32_bf16(qh[ks], bvh, aV, 0, 0, 0);
        }
        #pragma unroll
        for (int r = 0; r < 4; ++r) {
            const int i = (l >> 4) * 4 + r;
            const int j = j0 + fr;
            const float d  = facosh(fmaxf(aK[r], 1.0f + EPSF));
            const float al = fmaxf(aV[r], 1.0f + EPSF);
            const float e  = __expf(-d * d);
            const float p  = e * facosh(al);
            seLoc[r] += e;
            sPh[i][j] = cvt_rne(p);
        }
    }
    #pragma unroll
    for (int r = 0; r < 4; ++r) {
        float v = seLoc[r];
        v += __shfl_xor(v, 1, 64);
        v += __shfl_xor(v, 2, 64);
        v += __shfl_xor(v, 4, 64);
        v += __shfl_xor(v, 8, 64);
        if ((l & 15) == 0) sSe[w][(l >> 4) * 4 + r] = v;
    }
    __syncthreads();

    if (w < 6) {
        const int a0  = (w % 3) * 16;
        const int kh2 = w / 3;
        const long vb = (long)bh * 48 * Tq + (long)(a0 + fr) * Tq;
        f32x4 aW = (f32x4){0.f, 0.f, 0.f, 0.f};
        #pragma unroll 4
        for (int ks = kh2 * 8; ks < kh2 * 8 + 8; ++ks) {
            const int ko = ks * 32 + fk;
            const short8 ph  = *reinterpret_cast<const short8*>(&sPh[fr][ko]);
            const short8 v2h = *reinterpret_cast<const short8*>(&V2h[vb + ko]);
            aW = __builtin_amdgcn_mfma_f32_16x16x32_bf16(ph, v2h, aW, 0, 0, 0);
        }
        #pragma unroll
        for (int r = 0; r < 4; ++r)
            sWp[kh2][(l >> 4) * 4 + r][a0 + fr] = aW[r];
    }
    __syncthreads();

    if (t < 16) {
        const int i = t;
        float seT = 0.f;
        #pragma unroll
        for (int ww = 0; ww < 8; ++ww) seT += sSe[ww][i];
        float W[33];
        #pragma unroll
        for (int a = 0; a < 33; ++a) W[a] = sWp[0][i][a] + sWp[1][i][a];
        const float* qrow = Qf + (long)(bh * Tq + i0 + i) * QS;
        const float q0 = qrow[32];
        float dot = 0.f;
        #pragma unroll
        for (int a = 1; a < 33; ++a) dot = fmaf(qrow[a - 1], W[a], dot);
        const float S = q0 * W[0] - dot;
        const float cs = CINV * __builtin_amdgcn_rcpf(seT);
        const float y0 = fmaf(cs, fmaf(S, q0, W[0]), q0);
        float mink = -y0 * y0;
        float yv[32];
        #pragma unroll
        for (int a = 1; a < 33; ++a) {
            const float qa = qrow[a - 1];
            const float ya = fmaf(cs, fmaf(S, qa, W[a]), qa);
            yv[a - 1] = ya;
            mink = fmaf(ya, ya, mink);
        }
        const float inv = __builtin_amdgcn_rsqf(fmaxf(fabsf(mink), 1e-15f));
        const float Y0 = fabsf(y0 * inv);
        const float dist0 = facosh(fmaxf(Y0, 1.0f + EPSF));
        const float coef = dist0 * CINV;
        const int b = bh >> 3, h = bh & 7;
        float* zp = Ztan + ((b * Tq + (i0 + i)) * 264) + h * 33;
        zp[0] = coef * (2.0f * Y0);
        #pragma unroll
        for (int a = 1; a < 33; ++a) zp[a] = coef * (yv[a - 1] * inv);
    }
}

// ---------------- Kernel 3: out GEMM via MFMA hi/lo (R21) ------------------
__global__ __launch_bounds__(256) void out_gemm_mfma_kernel(
    const float* __restrict__ Ztan, const float* __restrict__ Wo,
    const float* __restrict__ bo, float* __restrict__ out)
{
    __shared__ unsigned short Ah[32][72], Al[32][72];
    __shared__ unsigned short Bh[32][72], Bl[32][72];

    const int n0 = blockIdx.x * 32;
    const int m0 = blockIdx.y * 32;
    const int t  = threadIdx.x;
    const int l  = t & 63, w = t >> 6;
    const int wr = (w >> 1) * 16, wc = (w & 1) * 16;
    const int fr = l & 15, fk = (l >> 4) * 8;

    const int sr = t >> 3, sk = (t & 7) * 8;

    f32x4 acc = (f32x4){0.f, 0.f, 0.f, 0.f};

    for (int k0 = 0; k0 < 264; k0 += 64) {
        const bool full = (k0 + sk + 7 < 264);
        {
            unsigned short h8[8], l8[8];
            if (full) {
                const float4 a0v = *reinterpret_cast<const float4*>(
                    &Ztan[(m0 + sr) * 264 + k0 + sk]);
                const float4 a1v = *reinterpret_cast<const float4*>(
                    &Ztan[(m0 + sr) * 264 + k0 + sk + 4]);
                cvt_hilo(a0v.x, h8[0], l8[0]); cvt_hilo(a0v.y, h8[1], l8[1]);
                cvt_hilo(a0v.z, h8[2], l8[2]); cvt_hilo(a0v.w, h8[3], l8[3]);
                cvt_hilo(a1v.x, h8[4], l8[4]); cvt_hilo(a1v.y, h8[5], l8[5]);
                cvt_hilo(a1v.z, h8[6], l8[6]); cvt_hilo(a1v.w, h8[7], l8[7]);
            } else {
                #pragma unroll
                for (int c = 0; c < 8; ++c) { h8[c] = 0; l8[c] = 0; }
            }
            *reinterpret_cast<uint4*>(&Ah[sr][sk]) = pack8(h8);
            *reinterpret_cast<uint4*>(&Al[sr][sk]) = pack8(l8);

            if (full) {
                const float4 b0v = *reinterpret_cast<const float4*>(
                    &Wo[(n0 + sr) * 264 + k0 + sk]);
                const float4 b1v = *reinterpret_cast<const float4*>(
                    &Wo[(n0 + sr) * 264 + k0 + sk + 4]);
                cvt_hilo(b0v.x, h8[0], l8[0]); cvt_hilo(b0v.y, h8[1], l8[1]);
                cvt_hilo(b0v.z, h8[2], l8[2]); cvt_hilo(b0v.w, h8[3], l8[3]);
                cvt_hilo(b1v.x, h8[4], l8[4]); cvt_hilo(b1v.y, h8[5], l8[5]);
                cvt_hilo(b1v.z, h8[6], l8[6]); cvt_hilo(b1v.w, h8[7], l8[7]);
            } else {
                #pragma unroll
                for (int c = 0; c < 8; ++c) { h8[c] = 0; l8[c] = 0; }
            }
            *reinterpret_cast<uint4*>(&Bh[sr][sk]) = pack8(h8);
            *reinterpret_cast<uint4*>(&Bl[sr][sk]) = pack8(l8);
        }
        __syncthreads();

        #pragma unroll
        for (int ks = 0; ks < 2; ++ks) {
            const int kb = ks * 32 + fk;
            const short8 ah  = *reinterpret_cast<const short8*>(&Ah[wr + fr][kb]);
            const short8 al_ = *reinterpret_cast<const short8*>(&Al[wr + fr][kb]);
            const short8 bh  = *reinterpret_cast<const short8*>(&Bh[wc + fr][kb]);
            const short8 bl_ = *reinterpret_cast<const short8*>(&Bl[wc + fr][kb]);
            acc = __builtin_amdgcn_mfma_f32_16x16x32_bf16(ah, bh, acc, 0, 0, 0);
            acc = __builtin_amdgcn_mfma_f32_16x16x32_bf16(ah, bl_, acc, 0, 0, 0);
            acc = __builtin_amdgcn_mfma_f32_16x16x32_bf16(al_, bh, acc, 0, 0, 0);
        }
        __syncthreads();
    }

    const int col = n0 + wc + fr;
    const float bias = bo[col];
    #pragma unroll
    for (int r = 0; r < 4; ++r) {
        const int row = m0 + wr + (l >> 4) * 4 + r;
        out[row * 512 + col] = acc[r] + bias;
    }
}

} // namespace

// ---------------------------------------------------------------------------
extern "C" void kernel_launch(void* const* d_in, const int* in_sizes, int n_in,
                              void* d_out, int out_size, void* d_ws, size_t ws_size,
                              hipStream_t stream)
{
    const float* x  = (const float*)d_in[0];
    const float* Wq = (const float*)d_in[1];
    const float* bq = (const float*)d_in[2];
    const float* Wk = (const float*)d_in[3];
    const float* bk = (const float*)d_in[4];
    const float* Wv = (const float*)d_in[5];
    const float* bv = (const float*)d_in[6];
    const float* Wo = (const float*)d_in[7];
    const float* bo = (const float*)d_in[8];
    float* out = (float*)d_out;

    float* ws = (float*)d_ws;
    float* Qf = ws;                                   // 294912 f
    unsigned short* Qh  = (unsigned short*)(ws + 294912);   // 262144 f each
    unsigned short* Ql  = (unsigned short*)(ws + 557056);
    unsigned short* Kh  = (unsigned short*)(ws + 819200);
    unsigned short* Vh  = (unsigned short*)(ws + 1081344);
    unsigned short* V2h = (unsigned short*)(ws + 1343488);  // 196608 f
    float* Zt = ws + 1540096;                         // 270336 f

    gemm_qkv_mfma_kernel<<<dim3(12, 64), 256, 0, stream>>>(
        x, Wq, bq, Wk, bk, Wv, bv, Qf, Qh, Ql, Kh, Vh, V2h);
    attn_mfma_kernel<<<dim3(32, 16), 512, 0, stream>>>(
        Qf, Qh, Ql, Kh, Vh, V2h, Zt);
    out_gemm_mfma_kernel<<<dim3(16, 32), 256, 0, stream>>>(Zt, Wo, bo, out);
}

// Round 23
// 37.330 us; speedup vs baseline: 5.5796x; 1.1011x over previous
//
#include <hip/hip_runtime.h>
#include <math.h>

// ---------------------------------------------------------------------------
// LorentzSelfAttention — MI355X
//
// Degenerate-clamp simplification (verified analytically, passed R1-R22):
//   u_agg_i = C*(W_i + S_i*Q_i),  W_i = sum_j p_ij V_j,  p = exp(-d^2)*dist
//   S_i = -mink(Q_i, W_i)  [R9-verified identity]
//   Y_i = mink_normalize(Q_i + u_agg_i/sum_e), |time|
//   Ztan_i = dist0*C * (2*Y0, Ys)
//
// R23: precision-headroom harvest. absmax stayed bit-identical (1.05e6)
// through K-RNE/alpha-RNE/out-bf16 => output error dominated by the f32
// clamp path, NOT operand quantization. So: (1) qkv GEMM pure single-RNE
// bf16 (x-lo + W-lo dropped: 3->1 mfma/ks, Al/Bl staging gone, LDS 27->16KB);
// (2) attn score path single-RNE (ql.K term dropped: GEMM1 3->2 mfma, Ql
// buffer deleted). FL lift, P5, and out-GEMM hi/lo unchanged. R22 XCD
// swizzles kept. Revert plan if absmax > 5.75e6.
// ---------------------------------------------------------------------------

namespace {

constexpr int Tq = 512;
constexpr int QS = 36;            // padded f32 Q row stride

#define EPSF  1e-6f
#define CINV  3.16227766e7f       // 1/sqrt(1e-15)

using short8 = __attribute__((ext_vector_type(8))) short;
using f32x4  = __attribute__((ext_vector_type(4))) float;

__device__ __forceinline__ float facosh(float x) {
    return __logf(x + __builtin_amdgcn_sqrtf(fmaf(x, x, -1.0f)));
}

__device__ __forceinline__ void cvt_hilo(float x, unsigned short& h, unsigned short& l) {
    const unsigned u = __float_as_uint(x);
    h = (unsigned short)(u >> 16);
    const float xh = __uint_as_float(u & 0xFFFF0000u);
    l = (unsigned short)(__float_as_uint(x - xh) >> 16);
}

__device__ __forceinline__ unsigned short cvt_rne(float x) {
    const unsigned u = __float_as_uint(x);
    return (unsigned short)((u + 0x7FFFu + ((u >> 16) & 1u)) >> 16);
}

__device__ __forceinline__ uint4 pack8(const unsigned short* s) {
    uint4 r;
    r.x = (unsigned)s[0] | ((unsigned)s[1] << 16);
    r.y = (unsigned)s[2] | ((unsigned)s[3] << 16);
    r.z = (unsigned)s[4] | ((unsigned)s[5] << 16);
    r.w = (unsigned)s[6] | ((unsigned)s[7] << 16);
    return r;
}

// ---------------- Kernel 1: QKV GEMM, single-RNE bf16, 16x64 tiles ---------
__global__ __launch_bounds__(256) void gemm_qkv_mfma_kernel(
    const float* __restrict__ x,
    const float* __restrict__ Wq, const float* __restrict__ bq,
    const float* __restrict__ Wk, const float* __restrict__ bk,
    const float* __restrict__ Wv, const float* __restrict__ bv,
    float* __restrict__ Qf, unsigned short* __restrict__ Qh,
    unsigned short* __restrict__ Kh,
    unsigned short* __restrict__ Vh, unsigned short* __restrict__ V2h)
{
    __shared__ unsigned short Ah[16][72];
    __shared__ unsigned short Bh[64][72];
    __shared__ float sT[16][65];

    // XCD swizzle: 768 = 8 * 96
    const int bid = blockIdx.y * 12 + blockIdx.x;
    const int swz = (bid & 7) * 96 + (bid >> 3);
    const int n0 = (swz >> 6) * 64;
    const int m0 = (swz & 63) * 16;

    const int t  = threadIdx.x;
    const int l  = t & 63, w = t >> 6;
    const int wc = w * 16;
    const int fr = l & 15, fk = (l >> 4) * 8;

    const int arow = t >> 4, akseg = (t & 15) * 4;
    const int brow = t >> 2, bkseg = (t & 3) * 16;
    const int ob  = n0 + brow;
    const float* WselB = (ob < 256) ? Wq : (ob < 512 ? Wk : Wv);
    const int obr = ob & 255;

    f32x4 acc = (f32x4){0.f, 0.f, 0.f, 0.f};

    for (int k0 = 0; k0 < 512; k0 += 64) {
        {
            const float4 av = *reinterpret_cast<const float4*>(
                &x[(m0 + arow) * 512 + k0 + akseg]);
            uint2 H;
            H.x = (unsigned)cvt_rne(av.x) | ((unsigned)cvt_rne(av.y) << 16);
            H.y = (unsigned)cvt_rne(av.z) | ((unsigned)cvt_rne(av.w) << 16);
            *reinterpret_cast<uint2*>(&Ah[arow][akseg]) = H;

            const float* wp = WselB + obr * 512 + k0 + bkseg;
            unsigned short hh[16];
            #pragma unroll
            for (int c = 0; c < 4; ++c) {
                const float4 v = *reinterpret_cast<const float4*>(wp + c * 4);
                hh[c*4+0] = cvt_rne(v.x); hh[c*4+1] = cvt_rne(v.y);
                hh[c*4+2] = cvt_rne(v.z); hh[c*4+3] = cvt_rne(v.w);
            }
            *reinterpret_cast<uint4*>(&Bh[brow][bkseg])     = pack8(hh);
            *reinterpret_cast<uint4*>(&Bh[brow][bkseg + 8]) = pack8(hh + 8);
        }
        __syncthreads();

        #pragma unroll
        for (int ks = 0; ks < 2; ++ks) {
            const int kb = ks * 32 + fk;
            const short8 ah = *reinterpret_cast<const short8*>(&Ah[fr][kb]);
            const short8 bh = *reinterpret_cast<const short8*>(&Bh[wc + fr][kb]);
            acc = __builtin_amdgcn_mfma_f32_16x16x32_bf16(ah, bh, acc, 0, 0, 0);
        }
        __syncthreads();
    }

    #pragma unroll
    for (int r = 0; r < 4; ++r)
        sT[(l >> 4) * 4 + r][wc + fr] = acc[r];
    __syncthreads();

    if (t < 32) {
        const int m = t >> 1, half = t & 1;
        const int row = m0 + m;
        const int b = row >> 9, tt = row & 511;
        const int which = n0 >> 8;
        const int h = ((n0 & 255) >> 5) + half;
        const int bh2 = b * 8 + h;
        const float* bsel = (which == 0) ? bq : (which == 1 ? bk : bv);

        float ys[32];
        float s2 = 0.f;
        #pragma unroll
        for (int k = 0; k < 32; ++k) {
            ys[k] = sT[m][half * 32 + k] + bsel[h * 32 + k];
            s2 = fmaf(ys[k], ys[k], s2);
        }
        const float rr = __builtin_amdgcn_sqrtf(s2);
        const float rs = fminf(fmaxf(rr, 1e-12f), 18.0f);
        const float e  = __expf(rs);
        const float ei = __builtin_amdgcn_rcpf(e);
        const float ch = 0.5f * (e + ei);
        float sc = 0.5f * (e - ei) / rs;
        if (rs < 1e-3f) sc = fmaf(rs * rs, 1.0f / 6.0f, 1.0f);
        float y0 = ch;
        float mink = -y0 * y0;
        #pragma unroll
        for (int k = 0; k < 32; ++k) { ys[k] *= sc; mink = fmaf(ys[k], ys[k], mink); }
        const float inv = __builtin_amdgcn_rsqf(fmaxf(fabsf(mink), 1e-15f));
        y0 = fabsf(y0 * inv);

        const long rbase = (long)(bh2 * Tq + tt) * 64;
        unsigned short hbuf[64];
        #pragma unroll
        for (int k = 33; k < 64; ++k) hbuf[k] = 0;

        if (which == 0) {
            float* qp = Qf + (bh2 * Tq + tt) * QS;
            #pragma unroll
            for (int c = 0; c < 8; ++c) {
                float4 v4;
                v4.x = ys[c*4+0] * inv; v4.y = ys[c*4+1] * inv;
                v4.z = ys[c*4+2] * inv; v4.w = ys[c*4+3] * inv;
                *reinterpret_cast<float4*>(qp + c * 4) = v4;
                hbuf[c*4+0] = cvt_rne(v4.x); hbuf[c*4+1] = cvt_rne(v4.y);
                hbuf[c*4+2] = cvt_rne(v4.z); hbuf[c*4+3] = cvt_rne(v4.w);
            }
            float4 tail; tail.x = y0; tail.y = 0.f; tail.z = 0.f; tail.w = 0.f;
            *reinterpret_cast<float4*>(qp + 32) = tail;
            hbuf[32] = cvt_rne(y0);
            #pragma unroll
            for (int c = 0; c < 8; ++c)
                *reinterpret_cast<uint4*>(&Qh[rbase + c * 8]) = pack8(hbuf + c * 8);
        } else if (which == 1) {
            #pragma unroll
            for (int k = 0; k < 32; ++k)
                hbuf[k] = cvt_rne(-ys[k] * inv);
            hbuf[32] = cvt_rne(y0);
            #pragma unroll
            for (int c = 0; c < 8; ++c)
                *reinterpret_cast<uint4*>(&Kh[rbase + c * 8]) = pack8(hbuf + c * 8);
        } else {
            const long v2b = (long)bh2 * 48 * Tq + tt;
            #pragma unroll
            for (int k = 0; k < 32; ++k) {
                const float v = ys[k] * inv;
                hbuf[k] = cvt_rne(-v);
                V2h[v2b + (1 + k) * Tq] = cvt_rne(v);
            }
            hbuf[32] = cvt_rne(y0);
            V2h[v2b] = cvt_rne(y0);
            #pragma unroll
            for (int c = 0; c < 8; ++c)
                *reinterpret_cast<uint4*>(&Vh[rbase + c * 8]) = pack8(hbuf + c * 8);
        }
    }
}

// ---------------- Kernel 2: attention, 512 threads, XCD-swizzled -----------
__global__ __launch_bounds__(512) void attn_mfma_kernel(
    const float* __restrict__ Qf, const unsigned short* __restrict__ Qh,
    const unsigned short* __restrict__ Kh,
    const unsigned short* __restrict__ Vh, const unsigned short* __restrict__ V2h,
    float* __restrict__ Ztan)
{
    __shared__ unsigned short sPh[16][528];
    __shared__ float sSe[8][16];
    __shared__ float sWp[2][16][48];

    // XCD swizzle: 512 = 8 * 64
    const int bid = blockIdx.y * 32 + blockIdx.x;
    const int swz = (bid & 7) * 64 + (bid >> 3);
    const int bh = swz >> 5;
    const int i0 = (swz & 31) * 16;

    const int t  = threadIdx.x;
    const int l  = t & 63, w = t >> 6;
    const int fr = l & 15, fk = (l >> 4) * 8;

    short8 qh[2];
    {
        const long qb = (long)(bh * Tq + i0 + fr) * 64;
        #pragma unroll
        for (int ks = 0; ks < 2; ++ks)
            qh[ks] = *reinterpret_cast<const short8*>(&Qh[qb + ks * 32 + fk]);
    }

    float seLoc[4] = {0.f, 0.f, 0.f, 0.f};
    #pragma unroll
    for (int c = 0; c < 4; ++c) {
        const int j0 = (w * 4 + c) * 16;
        const long kb = (long)(bh * Tq + j0 + fr) * 64;
        f32x4 aK = (f32x4){0.f, 0.f, 0.f, 0.f};
        f32x4 aV = (f32x4){0.f, 0.f, 0.f, 0.f};
        #pragma unroll
        for (int ks = 0; ks < 2; ++ks) {
            const long o = kb + ks * 32 + fk;
            const short8 bkh = *reinterpret_cast<const short8*>(&Kh[o]);
            const short8 bvh = *reinterpret_cast<const short8*>(&Vh[o]);
            aK = __builtin_amdgcn_mfma_f32_16x16x32_bf16(qh[ks], bkh, aK, 0, 0, 0);
            aV = __builtin_amdgcn_mfma_f32_16x16x32_bf16(qh[ks], bvh, aV, 0, 0, 0);
        }
        #pragma unroll
        for (int r = 0; r < 4; ++r) {
            const int i = (l >> 4) * 4 + r;
            const int j = j0 + fr;
            const float d  = facosh(fmaxf(aK[r], 1.0f + EPSF));
            const float al = fmaxf(aV[r], 1.0f + EPSF);
            const float e  = __expf(-d * d);
            const float p  = e * facosh(al);
            seLoc[r] += e;
            sPh[i][j] = cvt_rne(p);
        }
    }
    #pragma unroll
    for (int r = 0; r < 4; ++r) {
        float v = seLoc[r];
        v += __shfl_xor(v, 1, 64);
        v += __shfl_xor(v, 2, 64);
        v += __shfl_xor(v, 4, 64);
        v += __shfl_xor(v, 8, 64);
        if ((l & 15) == 0) sSe[w][(l >> 4) * 4 + r] = v;
    }
    __syncthreads();

    if (w < 6) {
        const int a0  = (w % 3) * 16;
        const int kh2 = w / 3;
        const long vb = (long)bh * 48 * Tq + (long)(a0 + fr) * Tq;
        f32x4 aW = (f32x4){0.f, 0.f, 0.f, 0.f};
        #pragma unroll 4
        for (int ks = kh2 * 8; ks < kh2 * 8 + 8; ++ks) {
            const int ko = ks * 32 + fk;
            const short8 ph  = *reinterpret_cast<const short8*>(&sPh[fr][ko]);
            const short8 v2h = *reinterpret_cast<const short8*>(&V2h[vb + ko]);
            aW = __builtin_amdgcn_mfma_f32_16x16x32_bf16(ph, v2h, aW, 0, 0, 0);
        }
        #pragma unroll
        for (int r = 0; r < 4; ++r)
            sWp[kh2][(l >> 4) * 4 + r][a0 + fr] = aW[r];
    }
    __syncthreads();

    if (t < 16) {
        const int i = t;
        float seT = 0.f;
        #pragma unroll
        for (int ww = 0; ww < 8; ++ww) seT += sSe[ww][i];
        float W[33];
        #pragma unroll
        for (int a = 0; a < 33; ++a) W[a] = sWp[0][i][a] + sWp[1][i][a];
        const float* qrow = Qf + (long)(bh * Tq + i0 + i) * QS;
        const float q0 = qrow[32];
        float dot = 0.f;
        #pragma unroll
        for (int a = 1; a < 33; ++a) dot = fmaf(qrow[a - 1], W[a], dot);
        const float S = q0 * W[0] - dot;
        const float cs = CINV * __builtin_amdgcn_rcpf(seT);
        const float y0 = fmaf(cs, fmaf(S, q0, W[0]), q0);
        float mink = -y0 * y0;
        float yv[32];
        #pragma unroll
        for (int a = 1; a < 33; ++a) {
            const float qa = qrow[a - 1];
            const float ya = fmaf(cs, fmaf(S, qa, W[a]), qa);
            yv[a - 1] = ya;
            mink = fmaf(ya, ya, mink);
        }
        const float inv = __builtin_amdgcn_rsqf(fmaxf(fabsf(mink), 1e-15f));
        const float Y0 = fabsf(y0 * inv);
        const float dist0 = facosh(fmaxf(Y0, 1.0f + EPSF));
        const float coef = dist0 * CINV;
        const int b = bh >> 3, h = bh & 7;
        float* zp = Ztan + ((b * Tq + (i0 + i)) * 264) + h * 33;
        zp[0] = coef * (2.0f * Y0);
        #pragma unroll
        for (int a = 1; a < 33; ++a) zp[a] = coef * (yv[a - 1] * inv);
    }
}

// ---------------- Kernel 3: out GEMM via MFMA hi/lo (R21) ------------------
__global__ __launch_bounds__(256) void out_gemm_mfma_kernel(
    const float* __restrict__ Ztan, const float* __restrict__ Wo,
    const float* __restrict__ bo, float* __restrict__ out)
{
    __shared__ unsigned short Ah[32][72], Al[32][72];
    __shared__ unsigned short Bh[32][72], Bl[32][72];

    const int n0 = blockIdx.x * 32;
    const int m0 = blockIdx.y * 32;
    const int t  = threadIdx.x;
    const int l  = t & 63, w = t >> 6;
    const int wr = (w >> 1) * 16, wc = (w & 1) * 16;
    const int fr = l & 15, fk = (l >> 4) * 8;

    const int sr = t >> 3, sk = (t & 7) * 8;

    f32x4 acc = (f32x4){0.f, 0.f, 0.f, 0.f};

    for (int k0 = 0; k0 < 264; k0 += 64) {
        const bool full = (k0 + sk + 7 < 264);
        {
            unsigned short h8[8], l8[8];
            if (full) {
                const float4 a0v = *reinterpret_cast<const float4*>(
                    &Ztan[(m0 + sr) * 264 + k0 + sk]);
                const float4 a1v = *reinterpret_cast<const float4*>(
                    &Ztan[(m0 + sr) * 264 + k0 + sk + 4]);
                cvt_hilo(a0v.x, h8[0], l8[0]); cvt_hilo(a0v.y, h8[1], l8[1]);
                cvt_hilo(a0v.z, h8[2], l8[2]); cvt_hilo(a0v.w, h8[3], l8[3]);
                cvt_hilo(a1v.x, h8[4], l8[4]); cvt_hilo(a1v.y, h8[5], l8[5]);
                cvt_hilo(a1v.z, h8[6], l8[6]); cvt_hilo(a1v.w, h8[7], l8[7]);
            } else {
                #pragma unroll
                for (int c = 0; c < 8; ++c) { h8[c] = 0; l8[c] = 0; }
            }
            *reinterpret_cast<uint4*>(&Ah[sr][sk]) = pack8(h8);
            *reinterpret_cast<uint4*>(&Al[sr][sk]) = pack8(l8);

            if (full) {
                const float4 b0v = *reinterpret_cast<const float4*>(
                    &Wo[(n0 + sr) * 264 + k0 + sk]);
                const float4 b1v = *reinterpret_cast<const float4*>(
                    &Wo[(n0 + sr) * 264 + k0 + sk + 4]);
                cvt_hilo(b0v.x, h8[0], l8[0]); cvt_hilo(b0v.y, h8[1], l8[1]);
                cvt_hilo(b0v.z, h8[2], l8[2]); cvt_hilo(b0v.w, h8[3], l8[3]);
                cvt_hilo(b1v.x, h8[4], l8[4]); cvt_hilo(b1v.y, h8[5], l8[5]);
                cvt_hilo(b1v.z, h8[6], l8[6]); cvt_hilo(b1v.w, h8[7], l8[7]);
            } else {
                #pragma unroll
                for (int c = 0; c < 8; ++c) { h8[c] = 0; l8[c] = 0; }
            }
            *reinterpret_cast<uint4*>(&Bh[sr][sk]) = pack8(h8);
            *reinterpret_cast<uint4*>(&Bl[sr][sk]) = pack8(l8);
        }
        __syncthreads();

        #pragma unroll
        for (int ks = 0; ks < 2; ++ks) {
            const int kb = ks * 32 + fk;
            const short8 ah  = *reinterpret_cast<const short8*>(&Ah[wr + fr][kb]);
            const short8 al_ = *reinterpret_cast<const short8*>(&Al[wr + fr][kb]);
            const short8 bh  = *reinterpret_cast<const short8*>(&Bh[wc + fr][kb]);
            const short8 bl_ = *reinterpret_cast<const short8*>(&Bl[wc + fr][kb]);
            acc = __builtin_amdgcn_mfma_f32_16x16x32_bf16(ah, bh, acc, 0, 0, 0);
            acc = __builtin_amdgcn_mfma_f32_16x16x32_bf16(ah, bl_, acc, 0, 0, 0);
            acc = __builtin_amdgcn_mfma_f32_16x16x32_bf16(al_, bh, acc, 0, 0, 0);
        }
        __syncthreads();
    }

    const int col = n0 + wc + fr;
    const float bias = bo[col];
    #pragma unroll
    for (int r = 0; r < 4; ++r) {
        const int row = m0 + wr + (l >> 4) * 4 + r;
        out[row * 512 + col] = acc[r] + bias;
    }
}

} // namespace

// ---------------------------------------------------------------------------
extern "C" void kernel_launch(void* const* d_in, const int* in_sizes, int n_in,
                              void* d_out, int out_size, void* d_ws, size_t ws_size,
                              hipStream_t stream)
{
    const float* x  = (const float*)d_in[0];
    const float* Wq = (const float*)d_in[1];
    const float* bq = (const float*)d_in[2];
    const float* Wk = (const float*)d_in[3];
    const float* bk = (const float*)d_in[4];
    const float* Wv = (const float*)d_in[5];
    const float* bv = (const float*)d_in[6];
    const float* Wo = (const float*)d_in[7];
    const float* bo = (const float*)d_in[8];
    float* out = (float*)d_out;

    float* ws = (float*)d_ws;
    float* Qf = ws;                                   // 294912 f
    unsigned short* Qh  = (unsigned short*)(ws + 294912);   // 262144 f each
    unsigned short* Kh  = (unsigned short*)(ws + 557056);
    unsigned short* Vh  = (unsigned short*)(ws + 819200);
    unsigned short* V2h = (unsigned short*)(ws + 1081344);  // 196608 f
    float* Zt = ws + 1277952;                         // 270336 f

    gemm_qkv_mfma_kernel<<<dim3(12, 64), 256, 0, stream>>>(
        x, Wq, bq, Wk, bk, Wv, bv, Qf, Qh, Kh, Vh, V2h);
    attn_mfma_kernel<<<dim3(32, 16), 512, 0, stream>>>(
        Qf, Qh, Kh, Vh, V2h, Zt);
    out_gemm_mfma_kernel<<<dim3(16, 32), 256, 0, stream>>>(Zt, Wo, bo, out);
}